// Round 6
// baseline (317.773 us; speedup 1.0000x reference)
//
#include <hip/hip_runtime.h>
#include <hip/hip_bf16.h>

#define B_ 64
#define S_ 512
#define H_ 1024
#define M_ 26
#define E_ 676

typedef short bf16x8 __attribute__((ext_vector_type(8)));
typedef float f32x4 __attribute__((ext_vector_type(4)));

__device__ __forceinline__ void gload16(const void* g, void* l) {
    __builtin_amdgcn_global_load_lds((const __attribute__((address_space(1))) unsigned int*)g,
                                     (__attribute__((address_space(3))) unsigned int*)l,
                                     16, 0, 0);
}

// fast tanh: 1 - 2/(exp(2x)+1)
__device__ __forceinline__ float tanh_fast(float x) {
    float e = __expf(2.0f * x);
    return 1.0f - 2.0f * __builtin_amdgcn_rcpf(e + 1.0f);
}

// ================= K_SEGMM: segment means as MFMA GEMM =================
// 256 blocks = 64 b x 4 h-chunks(256). Per block: C(32 x 256) = SEL(32 x 512) @ seq_slice.
// SEL built in LDS from offsets (1.0 exact in bf16, rows >= c zero). seq tiles of 32 t
// reg-staged (coalesced float4), 4x4-transposed in-reg, cvt bf16, ds_write b64 into
// [h][t] layout (Tpad=40 -> b128 frag reads 2-way conflict-free). MFMA f32 accum;
// epilogue: * exact f32 1/len -> bf16 -> nodeB. No atomics, no nodeS, no memset.
__global__ __launch_bounds__(256) void k_segmm(
    const float* __restrict__ seq, const int* __restrict__ off,
    __hip_bfloat16* __restrict__ nodeB) {
    __shared__ __hip_bfloat16 selL[32][520];       // 33.3 KB, row stride 1040B (16-aligned)
    __shared__ __hip_bfloat16 ldsB[2][256][40];    // 40.9 KB, row stride 80B (16-aligned)
    __shared__ int offs_s[28];
    __shared__ float invL[32];
    int tid = threadIdx.x;
    int bid = blockIdx.x;
    int b = bid >> 2, h0 = (bid & 3) * 256;
    int w = tid >> 6, l = tid & 63;

    if (tid < M_ - 1) offs_s[tid] = off[b * (M_ - 1) + tid];
    __syncthreads();
    int c = 0;                                     // uniform
    while (c < M_ - 1 && offs_s[c] > 0) c++;
    int offmax = offs_s[c - 1];                    // c >= 5 guaranteed

    // zero SEL
    {
        unsigned* p = (unsigned*)&selL[0][0];
        const int tot = 32 * 520 * 2 / 4;
        for (int i = tid; i < tot; i += 256) p[i] = 0u;
    }
    if (tid < 32)
        invL[tid] = (tid < c) ? 1.0f / (float)(offs_s[tid] - (tid ? offs_s[tid - 1] : 0))
                              : 0.0f;
    __syncthreads();
    // scatter 1.0 at SEL[m(t)][t] for t in [1, offmax]
    for (int t = tid; t < 512; t += 256) {
        if (t >= 1 && t <= offmax) {
            int ms = 0;
            while (ms < c && offs_s[ms] < t) ms++;
            if (ms < c) *(unsigned short*)&selL[ms][t] = 0x3F80;   // bf16 1.0
        }
    }
    __syncthreads();

    int nkt = (offmax >> 5) + 1;                   // k-tiles of 32 t, <= 16
    const float* sb = seq + (size_t)b * S_ * H_ + h0;
    float4 rg[8];
    // prologue: load tile 0 (wave w stages t-blocks {w, 4+w} of 4 rows x 256 h)
#pragma unroll
    for (int i = 0; i < 2; ++i)
#pragma unroll
        for (int r = 0; r < 4; ++r) {
            int tl = (i * 4 + w) * 4 + r;
            rg[i * 4 + r] = *(const float4*)(sb + (size_t)tl * H_ + 4 * l);
        }
    f32x4 acc[2][4] = {};                          // [m-tile][n-tile]

    for (int kt = 0; kt < nkt; ++kt) {
        asm volatile("s_waitcnt vmcnt(0)" ::: "memory");   // tile kt regs ready
        // cvt + 4x4 transpose into packed bf16 quads (all indices static)
        ushort4 pk[2][4];
#pragma unroll
        for (int i = 0; i < 2; ++i)
#pragma unroll
            for (int q = 0; q < 4; ++q) {
                float f0 = (q==0)?rg[i*4+0].x:(q==1)?rg[i*4+0].y:(q==2)?rg[i*4+0].z:rg[i*4+0].w;
                float f1 = (q==0)?rg[i*4+1].x:(q==1)?rg[i*4+1].y:(q==2)?rg[i*4+1].z:rg[i*4+1].w;
                float f2 = (q==0)?rg[i*4+2].x:(q==1)?rg[i*4+2].y:(q==2)?rg[i*4+2].z:rg[i*4+2].w;
                float f3 = (q==0)?rg[i*4+3].x:(q==1)?rg[i*4+3].y:(q==2)?rg[i*4+3].z:rg[i*4+3].w;
                __hip_bfloat16 __attribute__((aligned(8))) hh[4] = {
                    __float2bfloat16(f0), __float2bfloat16(f1),
                    __float2bfloat16(f2), __float2bfloat16(f3)};
                pk[i][q] = *(const ushort4*)hh;
            }
        // issue next tile's loads early (overlap with ds_write + MFMA below)
        if (kt + 1 < nkt) {
#pragma unroll
            for (int i = 0; i < 2; ++i)
#pragma unroll
                for (int r = 0; r < 4; ++r) {
                    int tl = (kt + 1) * 32 + (i * 4 + w) * 4 + r;
                    rg[i * 4 + r] = *(const float4*)(sb + (size_t)tl * H_ + 4 * l);
                }
            __builtin_amdgcn_sched_barrier(0);     // pin load issue here
        }
        // transposed store: column q of lane's 4x4 -> ldsB[4l+q][tb*4 .. +3]
#pragma unroll
        for (int i = 0; i < 2; ++i)
#pragma unroll
            for (int q = 0; q < 4; ++q) {
                int hl = 4 * l + q;
                int tb = i * 4 + w;
                *(ushort4*)&ldsB[kt & 1][hl][tb * 4] = pk[i][q];
            }
        asm volatile("s_waitcnt lgkmcnt(0)" ::: "memory");
        __builtin_amdgcn_s_barrier();              // tile kt visible block-wide
        // MFMA: one K=32 step per tile; wave w owns h-cols [w*64, w*64+64)
        int T0 = kt * 32;
#pragma unroll
        for (int mt = 0; mt < 2; ++mt) {
            bf16x8 af = *(const bf16x8*)&selL[mt * 16 + (l & 15)][T0 + (l >> 4) * 8];
#pragma unroll
            for (int nn = 0; nn < 4; ++nn) {
                bf16x8 bfr = *(const bf16x8*)&ldsB[kt & 1][(w * 4 + nn) * 16 + (l & 15)]
                                                  [(l >> 4) * 8];
                acc[mt][nn] = __builtin_amdgcn_mfma_f32_16x16x32_bf16(af, bfr,
                                                                      acc[mt][nn], 0, 0, 0);
            }
        }
        // no end barrier needed: next write targets the other buffer; the mid-barrier
        // of the following iteration separates those reads/writes.
    }
    // epilogue: mean -> bf16 -> nodeB (rows >= c give 0 * 0 = 0)
#pragma unroll
    for (int mt = 0; mt < 2; ++mt)
#pragma unroll
        for (int nn = 0; nn < 4; ++nn) {
            f32x4 v = acc[mt][nn];
            int hcol = h0 + (w * 4 + nn) * 16 + (l & 15);
#pragma unroll
            for (int r = 0; r < 4; ++r) {
                int m = mt * 16 + (l >> 4) * 4 + r;
                if (m < M_)
                    nodeB[((size_t)(b * M_ + m)) * H_ + hcol] =
                        __float2bfloat16(v[r] * invL[m]);
            }
        }
}

// ================= K_STAGE1B: cls GEMM | prep Wt | count | econ =================
// blocks [0,256) cls GEMM; [256,3328) prep; 3328 count; 3329 econ
__global__ __launch_bounds__(256) void k_stage1b(
    const float* __restrict__ seq, const int* __restrict__ off,
    const float* __restrict__ Wnaf, const float* __restrict__ Wcd,
    const float* __restrict__ Wnd, const float* __restrict__ Wed,
    const float* __restrict__ bed, const float* __restrict__ Weo,
    const float* __restrict__ beo,
    __hip_bfloat16* __restrict__ Wt, int* __restrict__ count,
    float* __restrict__ econ, float* __restrict__ naf, float* __restrict__ cdh) {
    __shared__ float smem[2048];
    int bid = blockIdx.x;
    int tid = threadIdx.x;

    if (bid < 256) {
        // ---- cls GEMM split-K into ZEROED naf|cdh ----
        float (*As)[64] = (float(*)[64])smem;
        float (*Bs)[64] = (float(*)[64])(smem + 1024);
        int bx = bid & 31;
        int kbase = (bid >> 5) * 128;
        const float* W;
        float* dst;
        int cbase;
        if (bx < 16) { W = Wnaf; dst = naf; cbase = bx * 64; }
        else         { W = Wcd;  dst = cdh; cbase = (bx - 16) * 64; }
        int tx = tid % 16, ty = tid / 16;
        float c[4][4] = {};
        int la_row = tid / 4;
        int la_k4  = (tid % 4) * 4;
        int lb_k   = tid / 16;
        int lb_c4  = (tid % 16) * 4;
        for (int k0 = 0; k0 < 128; k0 += 16) {
            float4 a = *(const float4*)(seq + (size_t)la_row * S_ * H_ + kbase + k0 + la_k4);
            *(float4*)(&Bs[lb_k][lb_c4]) =
                *(const float4*)(W + (size_t)(kbase + k0 + lb_k) * H_ + cbase + lb_c4);
            As[la_k4 + 0][la_row] = a.x;
            As[la_k4 + 1][la_row] = a.y;
            As[la_k4 + 2][la_row] = a.z;
            As[la_k4 + 3][la_row] = a.w;
            __syncthreads();
#pragma unroll
            for (int kk = 0; kk < 16; ++kk) {
                float4 av = *(const float4*)(&As[kk][ty * 4]);
                float4 bv = *(const float4*)(&Bs[kk][tx * 4]);
                c[0][0] += av.x * bv.x; c[0][1] += av.x * bv.y; c[0][2] += av.x * bv.z; c[0][3] += av.x * bv.w;
                c[1][0] += av.y * bv.x; c[1][1] += av.y * bv.y; c[1][2] += av.y * bv.z; c[1][3] += av.y * bv.w;
                c[2][0] += av.z * bv.x; c[2][1] += av.z * bv.y; c[2][2] += av.z * bv.z; c[2][3] += av.z * bv.w;
                c[3][0] += av.w * bv.x; c[3][1] += av.w * bv.y; c[3][2] += av.w * bv.z; c[3][3] += av.w * bv.w;
            }
            __syncthreads();
        }
#pragma unroll
        for (int i = 0; i < 4; ++i)
#pragma unroll
            for (int j = 0; j < 4; ++j)
                atomicAdd(dst + (size_t)(ty * 4 + i) * H_ + cbase + tx * 4 + j, c[i][j]);
    } else if (bid < 3328) {
        // ---- prep: Wt (3072 x 1024 bf16) = transposed [Wnd ; W1+W3 ; W2-W3] ----
        float (*T)[33] = (float(*)[33])smem;
        int idx = bid - 256;
        int s = idx >> 10, rem = idx & 1023;
        int bx = rem & 31, by = rem >> 5;
        int c = tid & 31, r0 = tid >> 5;
        const int HH = H_ * H_;
#pragma unroll
        for (int i = 0; i < 4; ++i) {
            int r = r0 + 8 * i;
            size_t k = by * 32 + r, n = bx * 32 + c;
            float v;
            if (s == 0)      v = Wnd[k * H_ + n];
            else if (s == 1) v = Wed[k * H_ + n] + Wed[2 * HH + k * H_ + n];
            else             v = Wed[HH + k * H_ + n] - Wed[2 * HH + k * H_ + n];
            T[r][c] = v;
        }
        __syncthreads();
#pragma unroll
        for (int i = 0; i < 4; ++i) {
            int rr = r0 + 8 * i;
            Wt[(size_t)(s * H_ + bx * 32 + rr) * H_ + by * 32 + c] = __float2bfloat16(T[c][rr]);
        }
    } else if (bid == 3328) {
        // ---- count ----
        if (tid < 64) {
            int b = tid;
            int c = 0;
            for (int m = 0; m < M_ - 1; ++m) c += (off[b * (M_ - 1) + m] > 0) ? 1 : 0;
            count[b] = c;
        }
    } else {
        // ---- invalid-edge constant logits: tanh(b_ed) @ W_eo + b_eo ----
        float* s0 = smem; float* s1 = smem + 256;
        float a0 = 0.f, a1 = 0.f;
        for (int h = tid; h < H_; h += 256) {
            float t = tanh_fast(bed[h]);
            a0 += t * Weo[h * 2 + 0];
            a1 += t * Weo[h * 2 + 1];
        }
        s0[tid] = a0; s1[tid] = a1; __syncthreads();
        for (int o = 128; o > 0; o >>= 1) {
            if (tid < o) { s0[tid] += s0[tid + o]; s1[tid] += s1[tid + o]; }
            __syncthreads();
        }
        if (tid == 0) { econ[0] = s0[0] + beo[0]; econ[1] = s1[0] + beo[1]; }
    }
}

// ================= K_STAGE2S: naf row -> nodeB (overwrite) | cls logits =================
// [0,64) naf row bf16 (b = bid); [64,128) cls logits (b = bid-64)
__global__ __launch_bounds__(256) void k_stage2s(
    const float* __restrict__ naf, const float* __restrict__ bnaf,
    const int* __restrict__ count, __hip_bfloat16* __restrict__ nodeB,
    const float* __restrict__ cdh, const float* __restrict__ bcd,
    const float* __restrict__ Wco, const float* __restrict__ bco,
    float* __restrict__ out) {
    __shared__ float smem[512];
    int bid = blockIdx.x;
    int tid = threadIdx.x;
    if (bid < 64) {
        int b = bid, cnt = count[b];
        float4 a = ((const float4*)(naf + (size_t)b * H_))[tid];
        float4 bb = ((const float4*)bnaf)[tid];
        __hip_bfloat16 __attribute__((aligned(8))) h[4] = {
            __float2bfloat16(a.x + bb.x), __float2bfloat16(a.y + bb.y),
            __float2bfloat16(a.z + bb.z), __float2bfloat16(a.w + bb.w)};
        *(ushort4*)(nodeB + ((size_t)(b * M_ + cnt)) * H_ + tid * 4) = *(const ushort4*)h;
    } else {
        int b = bid - 64;
        float* s0 = smem; float* s1 = smem + 256;
        float a0 = 0.f, a1 = 0.f;
        for (int h = tid; h < H_; h += 256) {
            float t = tanh_fast(cdh[(size_t)b * H_ + h] + bcd[h]);
            a0 += t * Wco[h * 2 + 0];
            a1 += t * Wco[h * 2 + 1];
        }
        s0[tid] = a0; s1[tid] = a1; __syncthreads();
        for (int o = 128; o > 0; o >>= 1) {
            if (tid < o) { s0[tid] += s0[tid + o]; s1[tid] += s1[tid + o]; }
            __syncthreads();
        }
        if (tid == 0) { out[b * 2 + 0] = s0[0] + bco[0]; out[b * 2 + 1] = s1[0] + bco[1]; }
    }
}

// ================= STAGE 3: MFMA GEMM C(1664x3072) = nodeB @ Wt^T =================
#define GM 1664
#define GN 3072
#define GK 1024
__global__ __launch_bounds__(256) void k_mfma(const __hip_bfloat16* __restrict__ A,
                                              const __hip_bfloat16* __restrict__ Bt,
                                              float* __restrict__ C) {
    __shared__ __hip_bfloat16 As[128 * 32];
    __shared__ __hip_bfloat16 Bs[128 * 32];
    int tid = threadIdx.x;
    int wid = tid >> 6, ln = tid & 63;
    int row0 = blockIdx.y * 128, col0 = blockIdx.x * 128;
    const __hip_bfloat16* ga = A + (size_t)(row0 + wid * 16 + (ln >> 2)) * GK + (ln & 3) * 8;
    const __hip_bfloat16* gb = Bt + (size_t)(col0 + wid * 16 + (ln >> 2)) * GK + (ln & 3) * 8;
    __hip_bfloat16* lA = As + wid * 512;
    __hip_bfloat16* lB = Bs + wid * 512;
    int mrow = (wid >> 1) * 64, ncol = (wid & 1) * 64;
    int l15 = ln & 15, l4 = ln >> 4;
    f32x4 acc[4][4] = {};
    const __hip_bfloat16* pa = As + (size_t)(mrow + l15) * 32 + l4 * 8;
    const __hip_bfloat16* pb = Bs + (size_t)(ncol + l15) * 32 + l4 * 8;
    for (int k0 = 0; k0 < GK; k0 += 32) {
        gload16(ga, lA);
        gload16(ga + 64 * GK, lA + 2048);
        gload16(gb, lB);
        gload16(gb + 64 * GK, lB + 2048);
        ga += 32; gb += 32;
        __syncthreads();
        bf16x8 af[4], bf[4];
#pragma unroll
        for (int mi = 0; mi < 4; ++mi) af[mi] = *(const bf16x8*)(pa + mi * 16 * 32);
#pragma unroll
        for (int ni = 0; ni < 4; ++ni) bf[ni] = *(const bf16x8*)(pb + ni * 16 * 32);
#pragma unroll
        for (int mi = 0; mi < 4; ++mi)
#pragma unroll
            for (int ni = 0; ni < 4; ++ni)
                acc[mi][ni] = __builtin_amdgcn_mfma_f32_16x16x32_bf16(af[mi], bf[ni],
                                                                      acc[mi][ni], 0, 0, 0);
        __syncthreads();
    }
#pragma unroll
    for (int mi = 0; mi < 4; ++mi)
#pragma unroll
        for (int ni = 0; ni < 4; ++ni) {
            f32x4 v = acc[mi][ni];
            size_t r = row0 + mrow + mi * 16 + l4 * 4;
            size_t cc = col0 + ncol + ni * 16 + l15;
            C[(r + 0) * GN + cc] = v[0];
            C[(r + 1) * GN + cc] = v[1];
            C[(r + 2) * GN + cc] = v[2];
            C[(r + 3) * GN + cc] = v[3];
        }
}

// ================= STAGE 4: node logits | edge logits =================
// blocks [0,416) node (4 rows each); [416,1440) edge (bx = e&15, b = e>>4)
__global__ __launch_bounds__(256) void k_stage4(
    const float* __restrict__ Cm, const int* __restrict__ count,
    const float* __restrict__ bnd, const float* __restrict__ Wno,
    const float* __restrict__ bno, const float* __restrict__ bed,
    const float* __restrict__ Weo, const float* __restrict__ beo,
    const float* __restrict__ econ, float* __restrict__ out_n,
    float* __restrict__ out_e) {
    int bid = blockIdx.x;
    int wid = threadIdx.x >> 6, lane = threadIdx.x & 63;
    if (bid < 416) {
        int r = bid * 4 + wid;
        const float4* src = (const float4*)(Cm + (size_t)r * GN);
        float a0 = 0.f, a1 = 0.f;
#pragma unroll
        for (int it = 0; it < 4; ++it) {
            int h = lane * 4 + it * 256;
            float4 s = src[lane + it * 64];
            float4 bb = *(const float4*)(bnd + h);
            float t0 = tanh_fast(s.x + bb.x), t1 = tanh_fast(s.y + bb.y);
            float t2 = tanh_fast(s.z + bb.z), t3 = tanh_fast(s.w + bb.w);
            a0 += t0 * Wno[h * 2 + 0] + t1 * Wno[h * 2 + 2] + t2 * Wno[h * 2 + 4] + t3 * Wno[h * 2 + 6];
            a1 += t0 * Wno[h * 2 + 1] + t1 * Wno[h * 2 + 3] + t2 * Wno[h * 2 + 5] + t3 * Wno[h * 2 + 7];
        }
        for (int o = 32; o > 0; o >>= 1) { a0 += __shfl_down(a0, o); a1 += __shfl_down(a1, o); }
        if (lane == 0) { out_n[(size_t)r * 2 + 0] = a0 + bno[0]; out_n[(size_t)r * 2 + 1] = a1 + bno[1]; }
    } else {
        int e = bid - 416;
        int b = e >> 4;
        int wg = (e & 15) * 4 + wid;
        int n = count[b] + 1;
        int n2 = n * n;
        float4 bed4[4], w04[4], w14[4];
#pragma unroll
        for (int it = 0; it < 4; ++it) {
            int h = lane * 4 + it * 256;
            bed4[it] = *(const float4*)(bed + h);
            w04[it] = make_float4(Weo[h * 2 + 0], Weo[h * 2 + 2], Weo[h * 2 + 4], Weo[h * 2 + 6]);
            w14[it] = make_float4(Weo[h * 2 + 1], Weo[h * 2 + 3], Weo[h * 2 + 5], Weo[h * 2 + 7]);
        }
        float e0 = econ[0], e1 = econ[1];
        float b0 = beo[0], b1 = beo[1];
        for (int k = wg; k < E_; k += 64) {
            float* dst = out_e + ((size_t)b * E_ + k) * 2;
            if (k >= n2) {
                if (lane == 0) { dst[0] = e0; dst[1] = e1; }
                continue;
            }
            int i = k / n, j = k - i * n;
            const float4* U4 = (const float4*)(Cm + (size_t)(b * M_ + j) * GN + H_);
            const float4* V4 = (const float4*)(Cm + (size_t)(b * M_ + i) * GN + 2 * H_);
            float a0 = 0.f, a1 = 0.f;
#pragma unroll
            for (int it = 0; it < 4; ++it) {
                float4 u = U4[lane + it * 64];
                float4 v = V4[lane + it * 64];
                float t0 = tanh_fast(u.x + v.x + bed4[it].x);
                float t1 = tanh_fast(u.y + v.y + bed4[it].y);
                float t2 = tanh_fast(u.z + v.z + bed4[it].z);
                float t3 = tanh_fast(u.w + v.w + bed4[it].w);
                a0 += t0 * w04[it].x + t1 * w04[it].y + t2 * w04[it].z + t3 * w04[it].w;
                a1 += t0 * w14[it].x + t1 * w14[it].y + t2 * w14[it].z + t3 * w14[it].w;
            }
            for (int o = 32; o > 0; o >>= 1) { a0 += __shfl_down(a0, o); a1 += __shfl_down(a1, o); }
            if (lane == 0) { dst[0] = a0 + b0; dst[1] = a1 + b1; }
        }
    }
}

extern "C" void kernel_launch(void* const* d_in, const int* in_sizes, int n_in,
                              void* d_out, int out_size, void* d_ws, size_t ws_size,
                              hipStream_t stream) {
    const float* seq  = (const float*)d_in[0];
    const int*   off  = (const int*)d_in[1];
    const float* Wnaf = (const float*)d_in[4];  const float* bnaf = (const float*)d_in[5];
    const float* Wcd  = (const float*)d_in[6];  const float* bcd  = (const float*)d_in[7];
    const float* Wco  = (const float*)d_in[8];  const float* bco  = (const float*)d_in[9];
    const float* Wnd  = (const float*)d_in[10]; const float* bnd  = (const float*)d_in[11];
    const float* Wno  = (const float*)d_in[12]; const float* bno  = (const float*)d_in[13];
    const float* Wed  = (const float*)d_in[14]; const float* bed  = (const float*)d_in[15];
    const float* Weo  = (const float*)d_in[16]; const float* beo  = (const float*)d_in[17];
    float* out = (float*)d_out;

    float* ws = (float*)d_ws;
    size_t p = 0;
    float* naf   = ws + p;  p += (size_t)B_ * H_;                // zeroed (acc)
    float* cdh   = ws + p;  p += (size_t)B_ * H_;                // zeroed (acc)
    __hip_bfloat16* nodeB = (__hip_bfloat16*)(ws + p); p += (size_t)B_ * M_ * H_ / 2;
    __hip_bfloat16* Wt    = (__hip_bfloat16*)(ws + p); p += (size_t)3 * H_ * H_ / 2;
    float* Cbuf  = ws + p;  p += (size_t)GM * GN;
    int*   cnt   = (int*)(ws + p); p += 64;
    float* econ  = ws + p;  p += 2;

    // only naf + cdh need zeroing (nodeB fully written by k_segmm + k_stage2s)
    hipMemsetAsync(naf, 0, 2 * (size_t)B_ * H_ * sizeof(float), stream);

    k_segmm<<<dim3(256), 256, 0, stream>>>(seq, off, nodeB);
    k_stage1b<<<dim3(3330), 256, 0, stream>>>(seq, off, Wnaf, Wcd, Wnd, Wed, bed, Weo, beo,
                                              Wt, cnt, econ, naf, cdh);
    k_stage2s<<<dim3(128), 256, 0, stream>>>(naf, bnaf, cnt, nodeB,
                                             cdh, bcd, Wco, bco, out);
    k_mfma<<<dim3(GN / 128, GM / 128), 256, 0, stream>>>(nodeB, Wt, Cbuf);
    k_stage4<<<dim3(1440), 256, 0, stream>>>(Cbuf, cnt, bnd, Wno, bno, bed, Weo, beo, econ,
                                             out + B_ * 2, out + B_ * 2 + B_ * M_ * 2);
}

// Round 7
// 310.360 us; speedup vs baseline: 1.0239x; 1.0239x over previous
//
#include <hip/hip_runtime.h>
#include <hip/hip_bf16.h>

#define B_ 64
#define S_ 512
#define H_ 1024
#define M_ 26
#define E_ 676

typedef short bf16x8 __attribute__((ext_vector_type(8)));
typedef float f32x4 __attribute__((ext_vector_type(4)));

__device__ __forceinline__ void gload16(const void* g, void* l) {
    __builtin_amdgcn_global_load_lds((const __attribute__((address_space(1))) unsigned int*)g,
                                     (__attribute__((address_space(3))) unsigned int*)l,
                                     16, 0, 0);
}

// fast tanh: 1 - 2/(exp(2x)+1)
__device__ __forceinline__ float tanh_fast(float x) {
    float e = __expf(2.0f * x);
    return 1.0f - 2.0f * __builtin_amdgcn_rcpf(e + 1.0f);
}

// ================= STAGE 1 (fused): MFMA seg | cls GEMM | prep Wt | count | econ ======
// [0,256)    segment means as MFMA GEMM -> nodeB bf16 (SEL in registers, 1-buf LDS)
// [256,512)  cls GEMM split-K into zeroed naf|cdh
// [512,3584) prep Wt (mayfly transpose blocks)
// 3584 count, 3585 econ
// Shared-LDS overlay: max branch = seg's 20.7 KB -> ~7 blocks/CU for the convoy.
__global__ __launch_bounds__(256) void k_stage1(
    const float* __restrict__ seq, const int* __restrict__ off,
    const float* __restrict__ Wnaf, const float* __restrict__ Wcd,
    const float* __restrict__ Wnd, const float* __restrict__ Wed,
    const float* __restrict__ bed, const float* __restrict__ Weo,
    const float* __restrict__ beo,
    __hip_bfloat16* __restrict__ Wt, int* __restrict__ count,
    float* __restrict__ econ, float* __restrict__ naf, float* __restrict__ cdh,
    __hip_bfloat16* __restrict__ nodeB) {
    __shared__ __attribute__((aligned(16))) char smraw[20992];
    int bid = blockIdx.x;
    int tid = threadIdx.x;

    if (bid < 256) {
        // ---- segment means via MFMA: C(32 x 256) = SEL(32 x 512) @ seq_slice ----
        __hip_bfloat16 (*ldsB)[40] = (__hip_bfloat16(*)[40])smraw;   // 256 x 40 bf16 = 20480B
        int* offs_s = (int*)(smraw + 20480);                         // 28 ints
        float* invL = (float*)(smraw + 20608);                       // 32 floats
        int b = bid >> 2, h0 = (bid & 3) * 256;
        int w = tid >> 6, l = tid & 63;

        if (tid < M_ - 1) offs_s[tid] = off[b * (M_ - 1) + tid];
        __syncthreads();
        int c = 0;                                     // uniform
        while (c < M_ - 1 && offs_s[c] > 0) c++;
        int offmax = offs_s[c - 1];                    // c >= 5 guaranteed
        if (tid < 32)
            invL[tid] = (tid < c) ? 1.0f / (float)(offs_s[tid] - (tid ? offs_s[tid - 1] : 0))
                                  : 0.0f;
        // per-lane SEL params for the lane's two A-rows (loop-invariant)
        int row0 = (l & 15), row1 = 16 + (l & 15);
        int offm0 = (row0 < c) ? offs_s[row0] : 0;
        int prv0  = (offm0 > 0) ? (row0 ? offs_s[row0 - 1] : 0) : 1;
        int offm1 = (row1 < c) ? offs_s[row1] : 0;
        int prv1  = (offm1 > 0) ? offs_s[row1 - 1] : 1;

        int nkt = (offmax >> 5) + 1;                   // k-tiles of 32 t, <= 16
        const float* sb = seq + (size_t)b * S_ * H_ + h0;
        float4 rg[8];
        // prologue: load tile 0 (wave w stages t-locals {4w..4w+3, 16+4w..16+4w+3})
#pragma unroll
        for (int i = 0; i < 2; ++i)
#pragma unroll
            for (int r = 0; r < 4; ++r)
                rg[i * 4 + r] = *(const float4*)(sb + (size_t)((i * 4 + w) * 4 + r) * H_ + 4 * l);
        f32x4 acc[2][4] = {};
        int tA = (l >> 4) * 8;                         // k-slice base within tile

        for (int kt = 0; kt < nkt; ++kt) {
            asm volatile("s_waitcnt vmcnt(0)" ::: "memory");   // tile kt regs ready
            // cvt + 4x4 transpose into packed bf16 quads (all indices static)
            ushort4 pk[2][4];
#pragma unroll
            for (int i = 0; i < 2; ++i)
#pragma unroll
                for (int q = 0; q < 4; ++q) {
                    float f0 = (q==0)?rg[i*4+0].x:(q==1)?rg[i*4+0].y:(q==2)?rg[i*4+0].z:rg[i*4+0].w;
                    float f1 = (q==0)?rg[i*4+1].x:(q==1)?rg[i*4+1].y:(q==2)?rg[i*4+1].z:rg[i*4+1].w;
                    float f2 = (q==0)?rg[i*4+2].x:(q==1)?rg[i*4+2].y:(q==2)?rg[i*4+2].z:rg[i*4+2].w;
                    float f3 = (q==0)?rg[i*4+3].x:(q==1)?rg[i*4+3].y:(q==2)?rg[i*4+3].z:rg[i*4+3].w;
                    __hip_bfloat16 __attribute__((aligned(8))) hh[4] = {
                        __float2bfloat16(f0), __float2bfloat16(f1),
                        __float2bfloat16(f2), __float2bfloat16(f3)};
                    pk[i][q] = *(const ushort4*)hh;
                }
            // issue next tile's loads early (overlap ds_write + MFMA)
            if (kt + 1 < nkt) {
#pragma unroll
                for (int i = 0; i < 2; ++i)
#pragma unroll
                    for (int r = 0; r < 4; ++r) {
                        int tl = (kt + 1) * 32 + (i * 4 + w) * 4 + r;
                        rg[i * 4 + r] = *(const float4*)(sb + (size_t)tl * H_ + 4 * l);
                    }
                __builtin_amdgcn_sched_barrier(0);     // pin load issue here
            }
            // transposed store: column q of lane's 4x4 -> ldsB[4l+q][tb*4 .. +3]
#pragma unroll
            for (int i = 0; i < 2; ++i)
#pragma unroll
                for (int q = 0; q < 4; ++q)
                    *(ushort4*)&ldsB[4 * l + q][(i * 4 + w) * 4] = pk[i][q];
            asm volatile("s_waitcnt lgkmcnt(0)" ::: "memory");
            __builtin_amdgcn_s_barrier();              // tile visible block-wide
            // SEL A-fragments in registers: 1.0 iff prv < t <= off
            int T0 = kt * 32;
            bf16x8 af0, af1;
#pragma unroll
            for (int i = 0; i < 8; ++i) {
                int t = T0 + tA + i;
                af0[i] = (t > prv0 && t <= offm0) ? (short)0x3F80 : (short)0;
                af1[i] = (t > prv1 && t <= offm1) ? (short)0x3F80 : (short)0;
            }
#pragma unroll
            for (int nn = 0; nn < 4; ++nn) {
                bf16x8 bfr = *(const bf16x8*)&ldsB[(w * 4 + nn) * 16 + (l & 15)][tA];
                acc[0][nn] = __builtin_amdgcn_mfma_f32_16x16x32_bf16(af0, bfr, acc[0][nn], 0, 0, 0);
                acc[1][nn] = __builtin_amdgcn_mfma_f32_16x16x32_bf16(af1, bfr, acc[1][nn], 0, 0, 0);
            }
            __builtin_amdgcn_s_barrier();              // reads done before next write
        }
        // epilogue: mean -> bf16 -> nodeB (rows >= c give 0 * 0 = 0)
#pragma unroll
        for (int mt = 0; mt < 2; ++mt)
#pragma unroll
            for (int nn = 0; nn < 4; ++nn) {
                f32x4 v = acc[mt][nn];
                int hcol = h0 + (w * 4 + nn) * 16 + (l & 15);
#pragma unroll
                for (int r = 0; r < 4; ++r) {
                    int m = mt * 16 + (l >> 4) * 4 + r;
                    if (m < M_)
                        nodeB[((size_t)(b * M_ + m)) * H_ + hcol] =
                            __float2bfloat16(v[r] * invL[m]);
                }
            }
    } else if (bid < 512) {
        // ---- cls GEMM split-K into ZEROED naf|cdh ----
        float* smem = (float*)smraw;
        float (*As)[64] = (float(*)[64])smem;
        float (*Bs)[64] = (float(*)[64])(smem + 1024);
        int e = bid - 256;
        int bx = e & 31;
        int kbase = (e >> 5) * 128;
        const float* W;
        float* dst;
        int cbase;
        if (bx < 16) { W = Wnaf; dst = naf; cbase = bx * 64; }
        else         { W = Wcd;  dst = cdh; cbase = (bx - 16) * 64; }
        int tx = tid % 16, ty = tid / 16;
        float c[4][4] = {};
        int la_row = tid / 4;
        int la_k4  = (tid % 4) * 4;
        int lb_k   = tid / 16;
        int lb_c4  = (tid % 16) * 4;
        for (int k0 = 0; k0 < 128; k0 += 16) {
            float4 a = *(const float4*)(seq + (size_t)la_row * S_ * H_ + kbase + k0 + la_k4);
            *(float4*)(&Bs[lb_k][lb_c4]) =
                *(const float4*)(W + (size_t)(kbase + k0 + lb_k) * H_ + cbase + lb_c4);
            As[la_k4 + 0][la_row] = a.x;
            As[la_k4 + 1][la_row] = a.y;
            As[la_k4 + 2][la_row] = a.z;
            As[la_k4 + 3][la_row] = a.w;
            __syncthreads();
#pragma unroll
            for (int kk = 0; kk < 16; ++kk) {
                float4 av = *(const float4*)(&As[kk][ty * 4]);
                float4 bv = *(const float4*)(&Bs[kk][tx * 4]);
                c[0][0] += av.x * bv.x; c[0][1] += av.x * bv.y; c[0][2] += av.x * bv.z; c[0][3] += av.x * bv.w;
                c[1][0] += av.y * bv.x; c[1][1] += av.y * bv.y; c[1][2] += av.y * bv.z; c[1][3] += av.y * bv.w;
                c[2][0] += av.z * bv.x; c[2][1] += av.z * bv.y; c[2][2] += av.z * bv.z; c[2][3] += av.z * bv.w;
                c[3][0] += av.w * bv.x; c[3][1] += av.w * bv.y; c[3][2] += av.w * bv.z; c[3][3] += av.w * bv.w;
            }
            __syncthreads();
        }
#pragma unroll
        for (int i = 0; i < 4; ++i)
#pragma unroll
            for (int j = 0; j < 4; ++j)
                atomicAdd(dst + (size_t)(ty * 4 + i) * H_ + cbase + tx * 4 + j, c[i][j]);
    } else if (bid < 3584) {
        // ---- prep: Wt (3072 x 1024 bf16) = transposed [Wnd ; W1+W3 ; W2-W3] ----
        float (*T)[33] = (float(*)[33])smraw;
        int idx = bid - 512;
        int s = idx >> 10, rem = idx & 1023;
        int bx = rem & 31, by = rem >> 5;
        int c = tid & 31, r0 = tid >> 5;
        const int HH = H_ * H_;
#pragma unroll
        for (int i = 0; i < 4; ++i) {
            int r = r0 + 8 * i;
            size_t k = by * 32 + r, n = bx * 32 + c;
            float v;
            if (s == 0)      v = Wnd[k * H_ + n];
            else if (s == 1) v = Wed[k * H_ + n] + Wed[2 * HH + k * H_ + n];
            else             v = Wed[HH + k * H_ + n] - Wed[2 * HH + k * H_ + n];
            T[r][c] = v;
        }
        __syncthreads();
#pragma unroll
        for (int i = 0; i < 4; ++i) {
            int rr = r0 + 8 * i;
            Wt[(size_t)(s * H_ + bx * 32 + rr) * H_ + by * 32 + c] = __float2bfloat16(T[c][rr]);
        }
    } else if (bid == 3584) {
        // ---- count ----
        if (tid < 64) {
            int b = tid;
            int c = 0;
            for (int m = 0; m < M_ - 1; ++m) c += (off[b * (M_ - 1) + m] > 0) ? 1 : 0;
            count[b] = c;
        }
    } else {
        // ---- invalid-edge constant logits: tanh(b_ed) @ W_eo + b_eo ----
        float* s0 = (float*)smraw; float* s1 = (float*)smraw + 256;
        float a0 = 0.f, a1 = 0.f;
        for (int h = tid; h < H_; h += 256) {
            float t = tanh_fast(bed[h]);
            a0 += t * Weo[h * 2 + 0];
            a1 += t * Weo[h * 2 + 1];
        }
        s0[tid] = a0; s1[tid] = a1; __syncthreads();
        for (int o = 128; o > 0; o >>= 1) {
            if (tid < o) { s0[tid] += s0[tid + o]; s1[tid] += s1[tid + o]; }
            __syncthreads();
        }
        if (tid == 0) { econ[0] = s0[0] + beo[0]; econ[1] = s1[0] + beo[1]; }
    }
}

// ================= K_STAGE2S: naf row -> nodeB (overwrite) | cls logits =================
// [0,64) naf row bf16 (b = bid); [64,128) cls logits (b = bid-64)
__global__ __launch_bounds__(256) void k_stage2s(
    const float* __restrict__ naf, const float* __restrict__ bnaf,
    const int* __restrict__ count, __hip_bfloat16* __restrict__ nodeB,
    const float* __restrict__ cdh, const float* __restrict__ bcd,
    const float* __restrict__ Wco, const float* __restrict__ bco,
    float* __restrict__ out) {
    __shared__ float smem[512];
    int bid = blockIdx.x;
    int tid = threadIdx.x;
    if (bid < 64) {
        int b = bid, cnt = count[b];
        float4 a = ((const float4*)(naf + (size_t)b * H_))[tid];
        float4 bb = ((const float4*)bnaf)[tid];
        __hip_bfloat16 __attribute__((aligned(8))) h[4] = {
            __float2bfloat16(a.x + bb.x), __float2bfloat16(a.y + bb.y),
            __float2bfloat16(a.z + bb.z), __float2bfloat16(a.w + bb.w)};
        *(ushort4*)(nodeB + ((size_t)(b * M_ + cnt)) * H_ + tid * 4) = *(const ushort4*)h;
    } else {
        int b = bid - 64;
        float* s0 = smem; float* s1 = smem + 256;
        float a0 = 0.f, a1 = 0.f;
        for (int h = tid; h < H_; h += 256) {
            float t = tanh_fast(cdh[(size_t)b * H_ + h] + bcd[h]);
            a0 += t * Wco[h * 2 + 0];
            a1 += t * Wco[h * 2 + 1];
        }
        s0[tid] = a0; s1[tid] = a1; __syncthreads();
        for (int o = 128; o > 0; o >>= 1) {
            if (tid < o) { s0[tid] += s0[tid + o]; s1[tid] += s1[tid + o]; }
            __syncthreads();
        }
        if (tid == 0) { out[b * 2 + 0] = s0[0] + bco[0]; out[b * 2 + 1] = s1[0] + bco[1]; }
    }
}

// ================= STAGE 3: MFMA GEMM C(1664x3072) = nodeB @ Wt^T =================
#define GM 1664
#define GN 3072
#define GK 1024
__global__ __launch_bounds__(256) void k_mfma(const __hip_bfloat16* __restrict__ A,
                                              const __hip_bfloat16* __restrict__ Bt,
                                              float* __restrict__ C) {
    __shared__ __hip_bfloat16 As[128 * 32];
    __shared__ __hip_bfloat16 Bs[128 * 32];
    int tid = threadIdx.x;
    int wid = tid >> 6, ln = tid & 63;
    int row0 = blockIdx.y * 128, col0 = blockIdx.x * 128;
    const __hip_bfloat16* ga = A + (size_t)(row0 + wid * 16 + (ln >> 2)) * GK + (ln & 3) * 8;
    const __hip_bfloat16* gb = Bt + (size_t)(col0 + wid * 16 + (ln >> 2)) * GK + (ln & 3) * 8;
    __hip_bfloat16* lA = As + wid * 512;
    __hip_bfloat16* lB = Bs + wid * 512;
    int mrow = (wid >> 1) * 64, ncol = (wid & 1) * 64;
    int l15 = ln & 15, l4 = ln >> 4;
    f32x4 acc[4][4] = {};
    const __hip_bfloat16* pa = As + (size_t)(mrow + l15) * 32 + l4 * 8;
    const __hip_bfloat16* pb = Bs + (size_t)(ncol + l15) * 32 + l4 * 8;
    for (int k0 = 0; k0 < GK; k0 += 32) {
        gload16(ga, lA);
        gload16(ga + 64 * GK, lA + 2048);
        gload16(gb, lB);
        gload16(gb + 64 * GK, lB + 2048);
        ga += 32; gb += 32;
        __syncthreads();
        bf16x8 af[4], bf[4];
#pragma unroll
        for (int mi = 0; mi < 4; ++mi) af[mi] = *(const bf16x8*)(pa + mi * 16 * 32);
#pragma unroll
        for (int ni = 0; ni < 4; ++ni) bf[ni] = *(const bf16x8*)(pb + ni * 16 * 32);
#pragma unroll
        for (int mi = 0; mi < 4; ++mi)
#pragma unroll
            for (int ni = 0; ni < 4; ++ni)
                acc[mi][ni] = __builtin_amdgcn_mfma_f32_16x16x32_bf16(af[mi], bf[ni],
                                                                      acc[mi][ni], 0, 0, 0);
        __syncthreads();
    }
#pragma unroll
    for (int mi = 0; mi < 4; ++mi)
#pragma unroll
        for (int ni = 0; ni < 4; ++ni) {
            f32x4 v = acc[mi][ni];
            size_t r = row0 + mrow + mi * 16 + l4 * 4;
            size_t cc = col0 + ncol + ni * 16 + l15;
            C[(r + 0) * GN + cc] = v[0];
            C[(r + 1) * GN + cc] = v[1];
            C[(r + 2) * GN + cc] = v[2];
            C[(r + 3) * GN + cc] = v[3];
        }
}

// ================= STAGE 4: node logits | edge logits =================
// blocks [0,416) node (4 rows each); [416,1440) edge (bx = e&15, b = e>>4)
__global__ __launch_bounds__(256) void k_stage4(
    const float* __restrict__ Cm, const int* __restrict__ count,
    const float* __restrict__ bnd, const float* __restrict__ Wno,
    const float* __restrict__ bno, const float* __restrict__ bed,
    const float* __restrict__ Weo, const float* __restrict__ beo,
    const float* __restrict__ econ, float* __restrict__ out_n,
    float* __restrict__ out_e) {
    int bid = blockIdx.x;
    int wid = threadIdx.x >> 6, lane = threadIdx.x & 63;
    if (bid < 416) {
        int r = bid * 4 + wid;
        const float4* src = (const float4*)(Cm + (size_t)r * GN);
        float a0 = 0.f, a1 = 0.f;
#pragma unroll
        for (int it = 0; it < 4; ++it) {
            int h = lane * 4 + it * 256;
            float4 s = src[lane + it * 64];
            float4 bb = *(const float4*)(bnd + h);
            float t0 = tanh_fast(s.x + bb.x), t1 = tanh_fast(s.y + bb.y);
            float t2 = tanh_fast(s.z + bb.z), t3 = tanh_fast(s.w + bb.w);
            a0 += t0 * Wno[h * 2 + 0] + t1 * Wno[h * 2 + 2] + t2 * Wno[h * 2 + 4] + t3 * Wno[h * 2 + 6];
            a1 += t0 * Wno[h * 2 + 1] + t1 * Wno[h * 2 + 3] + t2 * Wno[h * 2 + 5] + t3 * Wno[h * 2 + 7];
        }
        for (int o = 32; o > 0; o >>= 1) { a0 += __shfl_down(a0, o); a1 += __shfl_down(a1, o); }
        if (lane == 0) { out_n[(size_t)r * 2 + 0] = a0 + bno[0]; out_n[(size_t)r * 2 + 1] = a1 + bno[1]; }
    } else {
        int e = bid - 416;
        int b = e >> 4;
        int wg = (e & 15) * 4 + wid;
        int n = count[b] + 1;
        int n2 = n * n;
        float4 bed4[4], w04[4], w14[4];
#pragma unroll
        for (int it = 0; it < 4; ++it) {
            int h = lane * 4 + it * 256;
            bed4[it] = *(const float4*)(bed + h);
            w04[it] = make_float4(Weo[h * 2 + 0], Weo[h * 2 + 2], Weo[h * 2 + 4], Weo[h * 2 + 6]);
            w14[it] = make_float4(Weo[h * 2 + 1], Weo[h * 2 + 3], Weo[h * 2 + 5], Weo[h * 2 + 7]);
        }
        float e0 = econ[0], e1 = econ[1];
        float b0 = beo[0], b1 = beo[1];
        for (int k = wg; k < E_; k += 64) {
            float* dst = out_e + ((size_t)b * E_ + k) * 2;
            if (k >= n2) {
                if (lane == 0) { dst[0] = e0; dst[1] = e1; }
                continue;
            }
            int i = k / n, j = k - i * n;
            const float4* U4 = (const float4*)(Cm + (size_t)(b * M_ + j) * GN + H_);
            const float4* V4 = (const float4*)(Cm + (size_t)(b * M_ + i) * GN + 2 * H_);
            float a0 = 0.f, a1 = 0.f;
#pragma unroll
            for (int it = 0; it < 4; ++it) {
                float4 u = U4[lane + it * 64];
                float4 v = V4[lane + it * 64];
                float t0 = tanh_fast(u.x + v.x + bed4[it].x);
                float t1 = tanh_fast(u.y + v.y + bed4[it].y);
                float t2 = tanh_fast(u.z + v.z + bed4[it].z);
                float t3 = tanh_fast(u.w + v.w + bed4[it].w);
                a0 += t0 * w04[it].x + t1 * w04[it].y + t2 * w04[it].z + t3 * w04[it].w;
                a1 += t0 * w14[it].x + t1 * w14[it].y + t2 * w14[it].z + t3 * w14[it].w;
            }
            for (int o = 32; o > 0; o >>= 1) { a0 += __shfl_down(a0, o); a1 += __shfl_down(a1, o); }
            if (lane == 0) { dst[0] = a0 + b0; dst[1] = a1 + b1; }
        }
    }
}

extern "C" void kernel_launch(void* const* d_in, const int* in_sizes, int n_in,
                              void* d_out, int out_size, void* d_ws, size_t ws_size,
                              hipStream_t stream) {
    const float* seq  = (const float*)d_in[0];
    const int*   off  = (const int*)d_in[1];
    const float* Wnaf = (const float*)d_in[4];  const float* bnaf = (const float*)d_in[5];
    const float* Wcd  = (const float*)d_in[6];  const float* bcd  = (const float*)d_in[7];
    const float* Wco  = (const float*)d_in[8];  const float* bco  = (const float*)d_in[9];
    const float* Wnd  = (const float*)d_in[10]; const float* bnd  = (const float*)d_in[11];
    const float* Wno  = (const float*)d_in[12]; const float* bno  = (const float*)d_in[13];
    const float* Wed  = (const float*)d_in[14]; const float* bed  = (const float*)d_in[15];
    const float* Weo  = (const float*)d_in[16]; const float* beo  = (const float*)d_in[17];
    float* out = (float*)d_out;

    float* ws = (float*)d_ws;
    size_t p = 0;
    float* naf   = ws + p;  p += (size_t)B_ * H_;                // zeroed (acc)
    float* cdh   = ws + p;  p += (size_t)B_ * H_;                // zeroed (acc)
    __hip_bfloat16* nodeB = (__hip_bfloat16*)(ws + p); p += (size_t)B_ * M_ * H_ / 2;
    __hip_bfloat16* Wt    = (__hip_bfloat16*)(ws + p); p += (size_t)3 * H_ * H_ / 2;
    float* Cbuf  = ws + p;  p += (size_t)GM * GN;
    int*   cnt   = (int*)(ws + p); p += 64;
    float* econ  = ws + p;  p += 2;

    // only naf + cdh need zeroing (nodeB fully written by k_stage1 + k_stage2s)
    hipMemsetAsync(naf, 0, 2 * (size_t)B_ * H_ * sizeof(float), stream);

    k_stage1<<<dim3(3586), 256, 0, stream>>>(seq, off, Wnaf, Wcd, Wnd, Wed, bed, Weo, beo,
                                             Wt, cnt, econ, naf, cdh, nodeB);
    k_stage2s<<<dim3(128), 256, 0, stream>>>(naf, bnaf, cnt, nodeB,
                                             cdh, bcd, Wco, bco, out);
    k_mfma<<<dim3(GN / 128, GM / 128), 256, 0, stream>>>(nodeB, Wt, Cbuf);
    k_stage4<<<dim3(1440), 256, 0, stream>>>(Cbuf, cnt, bnd, Wno, bno, bed, Weo, beo, econ,
                                             out + B_ * 2, out + B_ * 2 + B_ * M_ * 2);
}

// Round 8
// 301.542 us; speedup vs baseline: 1.0538x; 1.0292x over previous
//
#include <hip/hip_runtime.h>
#include <hip/hip_bf16.h>

#define B_ 64
#define S_ 512
#define H_ 1024
#define M_ 26
#define E_ 676

typedef short bf16x8 __attribute__((ext_vector_type(8)));
typedef float f32x4 __attribute__((ext_vector_type(4)));

__device__ __forceinline__ void gload16(const void* g, void* l) {
    __builtin_amdgcn_global_load_lds((const __attribute__((address_space(1))) unsigned int*)g,
                                     (__attribute__((address_space(3))) unsigned int*)l,
                                     16, 0, 0);
}

// fast tanh: 1 - 2/(exp(2x)+1)
__device__ __forceinline__ float tanh_fast(float x) {
    float e = __expf(2.0f * x);
    return 1.0f - 2.0f * __builtin_amdgcn_rcpf(e + 1.0f);
}

// ================= STAGE 1 (fused): MFMA seg | cls slice GEMM | prep Wt | meta ======
// [0,256)    segment means as MFMA GEMM -> nodeB bf16 (SEL in registers, 1-buf LDS)
// [256,512)  cls GEMM split-K -> 8 PRIVATE slices (plain stores, no atomics/memset)
// [512,3584) prep Wt (mayfly transpose blocks)
// 3584 count + base prefix + rowmap; 3585 econ + nconst
__global__ __launch_bounds__(256) void k_stage1(
    const float* __restrict__ seq, const int* __restrict__ off,
    const float* __restrict__ Wnaf, const float* __restrict__ Wcd,
    const float* __restrict__ Wnd, const float* __restrict__ Wed,
    const float* __restrict__ bed, const float* __restrict__ Weo,
    const float* __restrict__ beo, const float* __restrict__ bnd,
    const float* __restrict__ Wno, const float* __restrict__ bno,
    __hip_bfloat16* __restrict__ Wt, int* __restrict__ count,
    int* __restrict__ base, int* __restrict__ rowmap,
    float* __restrict__ econ, float* __restrict__ nconst,
    float* __restrict__ naf8, float* __restrict__ cdh8,
    __hip_bfloat16* __restrict__ nodeB) {
    __shared__ __attribute__((aligned(16))) char smraw[20992];
    int bid = blockIdx.x;
    int tid = threadIdx.x;

    if (bid < 256) {
        // ---- segment means via MFMA: C(32 x 256) = SEL(32 x 512) @ seq_slice ----
        __hip_bfloat16 (*ldsB)[40] = (__hip_bfloat16(*)[40])smraw;   // 256 x 40 bf16
        int* offs_s = (int*)(smraw + 20480);
        float* invL = (float*)(smraw + 20608);
        int b = bid >> 2, h0 = (bid & 3) * 256;
        int w = tid >> 6, l = tid & 63;

        if (tid < M_ - 1) offs_s[tid] = off[b * (M_ - 1) + tid];
        __syncthreads();
        int c = 0;                                     // uniform
        while (c < M_ - 1 && offs_s[c] > 0) c++;
        int offmax = offs_s[c - 1];                    // c >= 5 guaranteed
        if (tid < 32)
            invL[tid] = (tid < c) ? 1.0f / (float)(offs_s[tid] - (tid ? offs_s[tid - 1] : 0))
                                  : 0.0f;
        int row0 = (l & 15), row1 = 16 + (l & 15);
        int offm0 = (row0 < c) ? offs_s[row0] : 0;
        int prv0  = (offm0 > 0) ? (row0 ? offs_s[row0 - 1] : 0) : 1;
        int offm1 = (row1 < c) ? offs_s[row1] : 0;
        int prv1  = (offm1 > 0) ? offs_s[row1 - 1] : 1;

        int nkt = (offmax >> 5) + 1;
        const float* sb = seq + (size_t)b * S_ * H_ + h0;
        float4 rg[8];
#pragma unroll
        for (int i = 0; i < 2; ++i)
#pragma unroll
            for (int r = 0; r < 4; ++r)
                rg[i * 4 + r] = *(const float4*)(sb + (size_t)((i * 4 + w) * 4 + r) * H_ + 4 * l);
        f32x4 acc[2][4] = {};
        int tA = (l >> 4) * 8;

        for (int kt = 0; kt < nkt; ++kt) {
            asm volatile("s_waitcnt vmcnt(0)" ::: "memory");
            ushort4 pk[2][4];
#pragma unroll
            for (int i = 0; i < 2; ++i)
#pragma unroll
                for (int q = 0; q < 4; ++q) {
                    float f0 = (q==0)?rg[i*4+0].x:(q==1)?rg[i*4+0].y:(q==2)?rg[i*4+0].z:rg[i*4+0].w;
                    float f1 = (q==0)?rg[i*4+1].x:(q==1)?rg[i*4+1].y:(q==2)?rg[i*4+1].z:rg[i*4+1].w;
                    float f2 = (q==0)?rg[i*4+2].x:(q==1)?rg[i*4+2].y:(q==2)?rg[i*4+2].z:rg[i*4+2].w;
                    float f3 = (q==0)?rg[i*4+3].x:(q==1)?rg[i*4+3].y:(q==2)?rg[i*4+3].z:rg[i*4+3].w;
                    __hip_bfloat16 __attribute__((aligned(8))) hh[4] = {
                        __float2bfloat16(f0), __float2bfloat16(f1),
                        __float2bfloat16(f2), __float2bfloat16(f3)};
                    pk[i][q] = *(const ushort4*)hh;
                }
            if (kt + 1 < nkt) {
#pragma unroll
                for (int i = 0; i < 2; ++i)
#pragma unroll
                    for (int r = 0; r < 4; ++r) {
                        int tl = (kt + 1) * 32 + (i * 4 + w) * 4 + r;
                        rg[i * 4 + r] = *(const float4*)(sb + (size_t)tl * H_ + 4 * l);
                    }
                __builtin_amdgcn_sched_barrier(0);
            }
#pragma unroll
            for (int i = 0; i < 2; ++i)
#pragma unroll
                for (int q = 0; q < 4; ++q)
                    *(ushort4*)&ldsB[4 * l + q][(i * 4 + w) * 4] = pk[i][q];
            asm volatile("s_waitcnt lgkmcnt(0)" ::: "memory");
            __builtin_amdgcn_s_barrier();
            int T0 = kt * 32;
            bf16x8 af0, af1;
#pragma unroll
            for (int i = 0; i < 8; ++i) {
                int t = T0 + tA + i;
                af0[i] = (t > prv0 && t <= offm0) ? (short)0x3F80 : (short)0;
                af1[i] = (t > prv1 && t <= offm1) ? (short)0x3F80 : (short)0;
            }
#pragma unroll
            for (int nn = 0; nn < 4; ++nn) {
                bf16x8 bfr = *(const bf16x8*)&ldsB[(w * 4 + nn) * 16 + (l & 15)][tA];
                acc[0][nn] = __builtin_amdgcn_mfma_f32_16x16x32_bf16(af0, bfr, acc[0][nn], 0, 0, 0);
                acc[1][nn] = __builtin_amdgcn_mfma_f32_16x16x32_bf16(af1, bfr, acc[1][nn], 0, 0, 0);
            }
            __builtin_amdgcn_s_barrier();
        }
        // epilogue: only rows m < c are ever read downstream (row c written by stage2s)
#pragma unroll
        for (int mt = 0; mt < 2; ++mt)
#pragma unroll
            for (int nn = 0; nn < 4; ++nn) {
                f32x4 v = acc[mt][nn];
                int hcol = h0 + (w * 4 + nn) * 16 + (l & 15);
#pragma unroll
                for (int r = 0; r < 4; ++r) {
                    int m = mt * 16 + (l >> 4) * 4 + r;
                    if (m < c)
                        nodeB[((size_t)(b * M_ + m)) * H_ + hcol] =
                            __float2bfloat16(v[r] * invL[m]);
                }
            }
    } else if (bid < 512) {
        // ---- cls GEMM split-K -> private slice (plain stores) ----
        float* smem = (float*)smraw;
        float (*As)[64] = (float(*)[64])smem;
        float (*Bs)[64] = (float(*)[64])(smem + 1024);
        int e = bid - 256;
        int bx = e & 31;
        int kg = e >> 5;
        int kbase = kg * 128;
        const float* W;
        float* dst;
        int cbase;
        if (bx < 16) { W = Wnaf; dst = naf8 + (size_t)kg * 64 * H_; cbase = bx * 64; }
        else         { W = Wcd;  dst = cdh8 + (size_t)kg * 64 * H_; cbase = (bx - 16) * 64; }
        int tx = tid % 16, ty = tid / 16;
        float c[4][4] = {};
        int la_row = tid / 4;
        int la_k4  = (tid % 4) * 4;
        int lb_k   = tid / 16;
        int lb_c4  = (tid % 16) * 4;
        for (int k0 = 0; k0 < 128; k0 += 16) {
            float4 a = *(const float4*)(seq + (size_t)la_row * S_ * H_ + kbase + k0 + la_k4);
            *(float4*)(&Bs[lb_k][lb_c4]) =
                *(const float4*)(W + (size_t)(kbase + k0 + lb_k) * H_ + cbase + lb_c4);
            As[la_k4 + 0][la_row] = a.x;
            As[la_k4 + 1][la_row] = a.y;
            As[la_k4 + 2][la_row] = a.z;
            As[la_k4 + 3][la_row] = a.w;
            __syncthreads();
#pragma unroll
            for (int kk = 0; kk < 16; ++kk) {
                float4 av = *(const float4*)(&As[kk][ty * 4]);
                float4 bv = *(const float4*)(&Bs[kk][tx * 4]);
                c[0][0] += av.x * bv.x; c[0][1] += av.x * bv.y; c[0][2] += av.x * bv.z; c[0][3] += av.x * bv.w;
                c[1][0] += av.y * bv.x; c[1][1] += av.y * bv.y; c[1][2] += av.y * bv.z; c[1][3] += av.y * bv.w;
                c[2][0] += av.z * bv.x; c[2][1] += av.z * bv.y; c[2][2] += av.z * bv.z; c[2][3] += av.z * bv.w;
                c[3][0] += av.w * bv.x; c[3][1] += av.w * bv.y; c[3][2] += av.w * bv.z; c[3][3] += av.w * bv.w;
            }
            __syncthreads();
        }
#pragma unroll
        for (int i = 0; i < 4; ++i) {
            float4 v = make_float4(c[i][0], c[i][1], c[i][2], c[i][3]);
            *(float4*)(dst + (size_t)(ty * 4 + i) * H_ + cbase + tx * 4) = v;
        }
    } else if (bid < 3584) {
        // ---- prep: Wt (3072 x 1024 bf16) = transposed [Wnd ; W1+W3 ; W2-W3] ----
        float (*T)[33] = (float(*)[33])smraw;
        int idx = bid - 512;
        int s = idx >> 10, rem = idx & 1023;
        int bx = rem & 31, by = rem >> 5;
        int c = tid & 31, r0 = tid >> 5;
        const int HH = H_ * H_;
#pragma unroll
        for (int i = 0; i < 4; ++i) {
            int r = r0 + 8 * i;
            size_t k = by * 32 + r, n = bx * 32 + c;
            float v;
            if (s == 0)      v = Wnd[k * H_ + n];
            else if (s == 1) v = Wed[k * H_ + n] + Wed[2 * HH + k * H_ + n];
            else             v = Wed[HH + k * H_ + n] - Wed[2 * HH + k * H_ + n];
            T[r][c] = v;
        }
        __syncthreads();
#pragma unroll
        for (int i = 0; i < 4; ++i) {
            int rr = r0 + 8 * i;
            Wt[(size_t)(s * H_ + bx * 32 + rr) * H_ + by * 32 + c] = __float2bfloat16(T[c][rr]);
        }
    } else if (bid == 3584) {
        // ---- count + base prefix + rowmap ----
        int* cnt_s = (int*)smraw;            // [64]
        int* base_s = (int*)smraw + 64;      // [65]
        if (tid < 64) {
            int b = tid, c = 0;
            for (int m = 0; m < M_ - 1; ++m) c += (off[b * (M_ - 1) + m] > 0) ? 1 : 0;
            cnt_s[b] = c; count[b] = c;
        }
        __syncthreads();
        if (tid == 0) {
            int a = 0;
            for (int b = 0; b < 64; ++b) { base_s[b] = a; a += cnt_s[b] + 1; }
            base_s[64] = a;
        }
        __syncthreads();
        if (tid < 65) base[tid] = base_s[tid];
        if (tid < 64) {
            int b = tid, bs = base_s[b];
            for (int m = 0; m <= cnt_s[b]; ++m) rowmap[bs + m] = b * M_ + m;
        }
    } else {
        // ---- constants: econ = tanh(bed)@Weo+beo ; nconst = tanh(bnd)@Wno+bno ----
        float* s0 = (float*)smraw; float* s1 = (float*)smraw + 256;
        float a0 = 0.f, a1 = 0.f;
        for (int h = tid; h < H_; h += 256) {
            float t = tanh_fast(bed[h]);
            a0 += t * Weo[h * 2 + 0];
            a1 += t * Weo[h * 2 + 1];
        }
        s0[tid] = a0; s1[tid] = a1; __syncthreads();
        for (int o = 128; o > 0; o >>= 1) {
            if (tid < o) { s0[tid] += s0[tid + o]; s1[tid] += s1[tid + o]; }
            __syncthreads();
        }
        if (tid == 0) { econ[0] = s0[0] + beo[0]; econ[1] = s1[0] + beo[1]; }
        __syncthreads();
        a0 = 0.f; a1 = 0.f;
        for (int h = tid; h < H_; h += 256) {
            float t = tanh_fast(bnd[h]);
            a0 += t * Wno[h * 2 + 0];
            a1 += t * Wno[h * 2 + 1];
        }
        s0[tid] = a0; s1[tid] = a1; __syncthreads();
        for (int o = 128; o > 0; o >>= 1) {
            if (tid < o) { s0[tid] += s0[tid + o]; s1[tid] += s1[tid + o]; }
            __syncthreads();
        }
        if (tid == 0) { nconst[0] = s0[0] + bno[0]; nconst[1] = s1[0] + bno[1]; }
    }
}

// ================= K_STAGE2S: sum cls slices -> naf row bf16 | cls logits =============
// [0,64) naf: nodeB[b*26+cnt] = sum_kg naf8[kg][b] + bnaf; [64,128) cls logits from cdh8
__global__ __launch_bounds__(256) void k_stage2s(
    const float* __restrict__ naf8, const float* __restrict__ cdh8,
    const float* __restrict__ bnaf, const int* __restrict__ count,
    __hip_bfloat16* __restrict__ nodeB,
    const float* __restrict__ bcd, const float* __restrict__ Wco,
    const float* __restrict__ bco, float* __restrict__ out) {
    __shared__ float smem[512];
    int bid = blockIdx.x;
    int tid = threadIdx.x;
    if (bid < 64) {
        int b = bid, cnt = count[b];
        float4 a = make_float4(0.f, 0.f, 0.f, 0.f);
#pragma unroll
        for (int kg = 0; kg < 8; ++kg) {
            float4 s = ((const float4*)(naf8 + (size_t)kg * 64 * H_ + (size_t)b * H_))[tid];
            a.x += s.x; a.y += s.y; a.z += s.z; a.w += s.w;
        }
        float4 bb = ((const float4*)bnaf)[tid];
        __hip_bfloat16 __attribute__((aligned(8))) h[4] = {
            __float2bfloat16(a.x + bb.x), __float2bfloat16(a.y + bb.y),
            __float2bfloat16(a.z + bb.z), __float2bfloat16(a.w + bb.w)};
        *(ushort4*)(nodeB + ((size_t)(b * M_ + cnt)) * H_ + tid * 4) = *(const ushort4*)h;
    } else {
        int b = bid - 64;
        float* s0 = smem; float* s1 = smem + 256;
        float a0 = 0.f, a1 = 0.f;
        for (int h = tid; h < H_; h += 256) {
            float v = 0.f;
#pragma unroll
            for (int kg = 0; kg < 8; ++kg) v += cdh8[(size_t)kg * 64 * H_ + (size_t)b * H_ + h];
            float t = tanh_fast(v + bcd[h]);
            a0 += t * Wco[h * 2 + 0];
            a1 += t * Wco[h * 2 + 1];
        }
        s0[tid] = a0; s1[tid] = a1; __syncthreads();
        for (int o = 128; o > 0; o >>= 1) {
            if (tid < o) { s0[tid] += s0[tid + o]; s1[tid] += s1[tid + o]; }
            __syncthreads();
        }
        if (tid == 0) { out[b * 2 + 0] = s0[0] + bco[0]; out[b * 2 + 1] = s1[0] + bco[1]; }
    }
}

// ================= STAGE 3: row-compacted MFMA GEMM C = gather(nodeB) @ Wt^T =========
#define GM 1664
#define GN 3072
#define GK 1024
__global__ __launch_bounds__(256) void k_mfma(const __hip_bfloat16* __restrict__ A,
                                              const __hip_bfloat16* __restrict__ Bt,
                                              float* __restrict__ C,
                                              const int* __restrict__ rowmap,
                                              const int* __restrict__ base) {
    __shared__ __hip_bfloat16 As[128 * 32];
    __shared__ __hip_bfloat16 Bs[128 * 32];
    int rowtotal = base[64];
    int row0 = blockIdx.y * 128;
    if (row0 >= rowtotal) return;          // block-uniform early exit
    int tid = threadIdx.x;
    int wid = tid >> 6, ln = tid & 63;
    int col0 = blockIdx.x * 128;
    int ai0 = row0 + wid * 16 + (ln >> 2);      if (ai0 > rowtotal - 1) ai0 = rowtotal - 1;
    int ai1 = row0 + 64 + wid * 16 + (ln >> 2); if (ai1 > rowtotal - 1) ai1 = rowtotal - 1;
    const __hip_bfloat16* ga0 = A + (size_t)rowmap[ai0] * GK + (ln & 3) * 8;
    const __hip_bfloat16* ga1 = A + (size_t)rowmap[ai1] * GK + (ln & 3) * 8;
    const __hip_bfloat16* gb = Bt + (size_t)(col0 + wid * 16 + (ln >> 2)) * GK + (ln & 3) * 8;
    __hip_bfloat16* lA = As + wid * 512;
    __hip_bfloat16* lB = Bs + wid * 512;
    int mrow = (wid >> 1) * 64, ncol = (wid & 1) * 64;
    int l15 = ln & 15, l4 = ln >> 4;
    f32x4 acc[4][4] = {};
    const __hip_bfloat16* pa = As + (size_t)(mrow + l15) * 32 + l4 * 8;
    const __hip_bfloat16* pb = Bs + (size_t)(ncol + l15) * 32 + l4 * 8;
    for (int k0 = 0; k0 < GK; k0 += 32) {
        gload16(ga0, lA);
        gload16(ga1, lA + 2048);
        gload16(gb, lB);
        gload16(gb + 64 * GK, lB + 2048);
        ga0 += 32; ga1 += 32; gb += 32;
        __syncthreads();
        bf16x8 af[4], bf[4];
#pragma unroll
        for (int mi = 0; mi < 4; ++mi) af[mi] = *(const bf16x8*)(pa + mi * 16 * 32);
#pragma unroll
        for (int ni = 0; ni < 4; ++ni) bf[ni] = *(const bf16x8*)(pb + ni * 16 * 32);
#pragma unroll
        for (int mi = 0; mi < 4; ++mi)
#pragma unroll
            for (int ni = 0; ni < 4; ++ni)
                acc[mi][ni] = __builtin_amdgcn_mfma_f32_16x16x32_bf16(af[mi], bf[ni],
                                                                      acc[mi][ni], 0, 0, 0);
        __syncthreads();
    }
#pragma unroll
    for (int mi = 0; mi < 4; ++mi)
#pragma unroll
        for (int ni = 0; ni < 4; ++ni) {
            f32x4 v = acc[mi][ni];
            int r = row0 + mrow + mi * 16 + l4 * 4;
            size_t cc = col0 + ncol + ni * 16 + l15;
#pragma unroll
            for (int j = 0; j < 4; ++j)
                if (r + j < rowtotal) C[(size_t)(r + j) * GN + cc] = v[j];
        }
}

// ================= STAGE 4: node logits | edge logits (compact C rows) ===============
// blocks [0,416) node (4 rows each); [416,1440) edge (bx = e&15, b = e>>4)
__global__ __launch_bounds__(256) void k_stage4(
    const float* __restrict__ Cm, const int* __restrict__ count,
    const int* __restrict__ base, const float* __restrict__ bnd,
    const float* __restrict__ Wno, const float* __restrict__ bno,
    const float* __restrict__ bed, const float* __restrict__ Weo,
    const float* __restrict__ beo, const float* __restrict__ econ,
    const float* __restrict__ nconst, float* __restrict__ out_n,
    float* __restrict__ out_e) {
    int bid = blockIdx.x;
    int wid = threadIdx.x >> 6, lane = threadIdx.x & 63;
    if (bid < 416) {
        int r = bid * 4 + wid;
        int b = r / 26, m = r - b * 26;
        if (m <= count[b]) {
            const float4* src = (const float4*)(Cm + (size_t)(base[b] + m) * GN);
            float a0 = 0.f, a1 = 0.f;
#pragma unroll
            for (int it = 0; it < 4; ++it) {
                int h = lane * 4 + it * 256;
                float4 s = src[lane + it * 64];
                float4 bb = *(const float4*)(bnd + h);
                float t0 = tanh_fast(s.x + bb.x), t1 = tanh_fast(s.y + bb.y);
                float t2 = tanh_fast(s.z + bb.z), t3 = tanh_fast(s.w + bb.w);
                a0 += t0 * Wno[h * 2 + 0] + t1 * Wno[h * 2 + 2] + t2 * Wno[h * 2 + 4] + t3 * Wno[h * 2 + 6];
                a1 += t0 * Wno[h * 2 + 1] + t1 * Wno[h * 2 + 3] + t2 * Wno[h * 2 + 5] + t3 * Wno[h * 2 + 7];
            }
            for (int o = 32; o > 0; o >>= 1) { a0 += __shfl_down(a0, o); a1 += __shfl_down(a1, o); }
            if (lane == 0) { out_n[(size_t)r * 2 + 0] = a0 + bno[0]; out_n[(size_t)r * 2 + 1] = a1 + bno[1]; }
        } else if (lane == 0) {
            out_n[(size_t)r * 2 + 0] = nconst[0];
            out_n[(size_t)r * 2 + 1] = nconst[1];
        }
    } else {
        int e = bid - 416;
        int b = e >> 4;
        int wg = (e & 15) * 4 + wid;
        int n = count[b] + 1;
        int n2 = n * n;
        int bb_ = base[b];
        float4 bed4[4], w04[4], w14[4];
#pragma unroll
        for (int it = 0; it < 4; ++it) {
            int h = lane * 4 + it * 256;
            bed4[it] = *(const float4*)(bed + h);
            w04[it] = make_float4(Weo[h * 2 + 0], Weo[h * 2 + 2], Weo[h * 2 + 4], Weo[h * 2 + 6]);
            w14[it] = make_float4(Weo[h * 2 + 1], Weo[h * 2 + 3], Weo[h * 2 + 5], Weo[h * 2 + 7]);
        }
        float e0 = econ[0], e1 = econ[1];
        float b0 = beo[0], b1 = beo[1];
        for (int k = wg; k < E_; k += 64) {
            float* dst = out_e + ((size_t)b * E_ + k) * 2;
            if (k >= n2) {
                if (lane == 0) { dst[0] = e0; dst[1] = e1; }
                continue;
            }
            int i = k / n, j = k - i * n;
            const float4* U4 = (const float4*)(Cm + (size_t)(bb_ + j) * GN + H_);
            const float4* V4 = (const float4*)(Cm + (size_t)(bb_ + i) * GN + 2 * H_);
            float a0 = 0.f, a1 = 0.f;
#pragma unroll
            for (int it = 0; it < 4; ++it) {
                float4 u = U4[lane + it * 64];
                float4 v = V4[lane + it * 64];
                float t0 = tanh_fast(u.x + v.x + bed4[it].x);
                float t1 = tanh_fast(u.y + v.y + bed4[it].y);
                float t2 = tanh_fast(u.z + v.z + bed4[it].z);
                float t3 = tanh_fast(u.w + v.w + bed4[it].w);
                a0 += t0 * w04[it].x + t1 * w04[it].y + t2 * w04[it].z + t3 * w04[it].w;
                a1 += t0 * w14[it].x + t1 * w14[it].y + t2 * w14[it].z + t3 * w14[it].w;
            }
            for (int o = 32; o > 0; o >>= 1) { a0 += __shfl_down(a0, o); a1 += __shfl_down(a1, o); }
            if (lane == 0) { dst[0] = a0 + b0; dst[1] = a1 + b1; }
        }
    }
}

extern "C" void kernel_launch(void* const* d_in, const int* in_sizes, int n_in,
                              void* d_out, int out_size, void* d_ws, size_t ws_size,
                              hipStream_t stream) {
    const float* seq  = (const float*)d_in[0];
    const int*   off  = (const int*)d_in[1];
    const float* Wnaf = (const float*)d_in[4];  const float* bnaf = (const float*)d_in[5];
    const float* Wcd  = (const float*)d_in[6];  const float* bcd  = (const float*)d_in[7];
    const float* Wco  = (const float*)d_in[8];  const float* bco  = (const float*)d_in[9];
    const float* Wnd  = (const float*)d_in[10]; const float* bnd  = (const float*)d_in[11];
    const float* Wno  = (const float*)d_in[12]; const float* bno  = (const float*)d_in[13];
    const float* Wed  = (const float*)d_in[14]; const float* bed  = (const float*)d_in[15];
    const float* Weo  = (const float*)d_in[16]; const float* beo  = (const float*)d_in[17];
    float* out = (float*)d_out;

    float* ws = (float*)d_ws;
    size_t p = 0;
    float* naf8  = ws + p;  p += (size_t)8 * 64 * H_;            // write-only slices
    float* cdh8  = ws + p;  p += (size_t)8 * 64 * H_;
    __hip_bfloat16* nodeB = (__hip_bfloat16*)(ws + p); p += (size_t)B_ * M_ * H_ / 2;
    __hip_bfloat16* Wt    = (__hip_bfloat16*)(ws + p); p += (size_t)3 * H_ * H_ / 2;
    float* Cbuf  = ws + p;  p += (size_t)GM * GN;
    int*   cnt   = (int*)(ws + p); p += 64;
    int*   base  = (int*)(ws + p); p += 65;
    int*   rowmap = (int*)(ws + p); p += GM;
    float* econ  = ws + p;  p += 2;
    float* nconst = ws + p; p += 2;

    // no memset needed: all consumed workspace is fully written before read

    k_stage1<<<dim3(3586), 256, 0, stream>>>(seq, off, Wnaf, Wcd, Wnd, Wed, bed, Weo, beo,
                                             bnd, Wno, bno, Wt, cnt, base, rowmap,
                                             econ, nconst, naf8, cdh8, nodeB);
    k_stage2s<<<dim3(128), 256, 0, stream>>>(naf8, cdh8, bnaf, cnt, nodeB,
                                             bcd, Wco, bco, out);
    k_mfma<<<dim3(GN / 128, GM / 128), 256, 0, stream>>>(nodeB, Wt, Cbuf, rowmap, base);
    k_stage4<<<dim3(1440), 256, 0, stream>>>(Cbuf, cnt, base, bnd, Wno, bno, bed, Weo, beo,
                                             econ, nconst,
                                             out + B_ * 2, out + B_ * 2 + B_ * M_ * 2);
}

// Round 9
// 296.321 us; speedup vs baseline: 1.0724x; 1.0176x over previous
//
#include <hip/hip_runtime.h>
#include <hip/hip_bf16.h>

#define B_ 64
#define S_ 512
#define H_ 1024
#define M_ 26
#define E_ 676

typedef short bf16x8 __attribute__((ext_vector_type(8)));
typedef float f32x4 __attribute__((ext_vector_type(4)));

__device__ __forceinline__ void gload16(const void* g, void* l) {
    __builtin_amdgcn_global_load_lds((const __attribute__((address_space(1))) unsigned int*)g,
                                     (__attribute__((address_space(3))) unsigned int*)l,
                                     16, 0, 0);
}

// fast tanh: 1 - 2/(exp(2x)+1)
__device__ __forceinline__ float tanh_fast(float x) {
    float e = __expf(2.0f * x);
    return 1.0f - 2.0f * __builtin_amdgcn_rcpf(e + 1.0f);
}

// ================= STAGE 1 (fused): MFMA seg | cls slice GEMM | prep Wt | meta ======
// [0,256)    segment means as MFMA GEMM -> nodeB bf16 (SEL in registers, 1-buf LDS)
// [256,512)  cls GEMM split-K -> 8 PRIVATE slices (plain stores, no atomics/memset)
// [512,3584) prep Wt (mayfly transpose blocks)
// 3584 count + base prefix + rowmap; 3585 econ + nconst
__global__ __launch_bounds__(256) void k_stage1(
    const float* __restrict__ seq, const int* __restrict__ off,
    const float* __restrict__ Wnaf, const float* __restrict__ Wcd,
    const float* __restrict__ Wnd, const float* __restrict__ Wed,
    const float* __restrict__ bed, const float* __restrict__ Weo,
    const float* __restrict__ beo, const float* __restrict__ bnd,
    const float* __restrict__ Wno, const float* __restrict__ bno,
    __hip_bfloat16* __restrict__ Wt, int* __restrict__ count,
    int* __restrict__ base, int* __restrict__ rowmap,
    float* __restrict__ econ, float* __restrict__ nconst,
    float* __restrict__ naf8, float* __restrict__ cdh8,
    __hip_bfloat16* __restrict__ nodeB) {
    __shared__ __attribute__((aligned(16))) char smraw[20992];
    int bid = blockIdx.x;
    int tid = threadIdx.x;

    if (bid < 256) {
        // ---- segment means via MFMA: C(32 x 256) = SEL(32 x 512) @ seq_slice ----
        __hip_bfloat16 (*ldsB)[40] = (__hip_bfloat16(*)[40])smraw;   // 256 x 40 bf16
        int* offs_s = (int*)(smraw + 20480);
        float* invL = (float*)(smraw + 20608);
        int b = bid >> 2, h0 = (bid & 3) * 256;
        int w = tid >> 6, l = tid & 63;

        if (tid < M_ - 1) offs_s[tid] = off[b * (M_ - 1) + tid];
        __syncthreads();
        int c = 0;                                     // uniform
        while (c < M_ - 1 && offs_s[c] > 0) c++;
        int offmax = offs_s[c - 1];                    // c >= 5 guaranteed
        if (tid < 32)
            invL[tid] = (tid < c) ? 1.0f / (float)(offs_s[tid] - (tid ? offs_s[tid - 1] : 0))
                                  : 0.0f;
        int row0 = (l & 15), row1 = 16 + (l & 15);
        int offm0 = (row0 < c) ? offs_s[row0] : 0;
        int prv0  = (offm0 > 0) ? (row0 ? offs_s[row0 - 1] : 0) : 1;
        int offm1 = (row1 < c) ? offs_s[row1] : 0;
        int prv1  = (offm1 > 0) ? offs_s[row1 - 1] : 1;

        int nkt = (offmax >> 5) + 1;
        const float* sb = seq + (size_t)b * S_ * H_ + h0;
        float4 rg[8];
#pragma unroll
        for (int i = 0; i < 2; ++i)
#pragma unroll
            for (int r = 0; r < 4; ++r)
                rg[i * 4 + r] = *(const float4*)(sb + (size_t)((i * 4 + w) * 4 + r) * H_ + 4 * l);
        f32x4 acc[2][4] = {};
        int tA = (l >> 4) * 8;

        for (int kt = 0; kt < nkt; ++kt) {
            asm volatile("s_waitcnt vmcnt(0)" ::: "memory");
            ushort4 pk[2][4];
#pragma unroll
            for (int i = 0; i < 2; ++i)
#pragma unroll
                for (int q = 0; q < 4; ++q) {
                    float f0 = (q==0)?rg[i*4+0].x:(q==1)?rg[i*4+0].y:(q==2)?rg[i*4+0].z:rg[i*4+0].w;
                    float f1 = (q==0)?rg[i*4+1].x:(q==1)?rg[i*4+1].y:(q==2)?rg[i*4+1].z:rg[i*4+1].w;
                    float f2 = (q==0)?rg[i*4+2].x:(q==1)?rg[i*4+2].y:(q==2)?rg[i*4+2].z:rg[i*4+2].w;
                    float f3 = (q==0)?rg[i*4+3].x:(q==1)?rg[i*4+3].y:(q==2)?rg[i*4+3].z:rg[i*4+3].w;
                    __hip_bfloat16 __attribute__((aligned(8))) hh[4] = {
                        __float2bfloat16(f0), __float2bfloat16(f1),
                        __float2bfloat16(f2), __float2bfloat16(f3)};
                    pk[i][q] = *(const ushort4*)hh;
                }
            if (kt + 1 < nkt) {
#pragma unroll
                for (int i = 0; i < 2; ++i)
#pragma unroll
                    for (int r = 0; r < 4; ++r) {
                        int tl = (kt + 1) * 32 + (i * 4 + w) * 4 + r;
                        rg[i * 4 + r] = *(const float4*)(sb + (size_t)tl * H_ + 4 * l);
                    }
                __builtin_amdgcn_sched_barrier(0);
            }
#pragma unroll
            for (int i = 0; i < 2; ++i)
#pragma unroll
                for (int q = 0; q < 4; ++q)
                    *(ushort4*)&ldsB[4 * l + q][(i * 4 + w) * 4] = pk[i][q];
            asm volatile("s_waitcnt lgkmcnt(0)" ::: "memory");
            __builtin_amdgcn_s_barrier();
            int T0 = kt * 32;
            bf16x8 af0, af1;
#pragma unroll
            for (int i = 0; i < 8; ++i) {
                int t = T0 + tA + i;
                af0[i] = (t > prv0 && t <= offm0) ? (short)0x3F80 : (short)0;
                af1[i] = (t > prv1 && t <= offm1) ? (short)0x3F80 : (short)0;
            }
#pragma unroll
            for (int nn = 0; nn < 4; ++nn) {
                bf16x8 bfr = *(const bf16x8*)&ldsB[(w * 4 + nn) * 16 + (l & 15)][tA];
                acc[0][nn] = __builtin_amdgcn_mfma_f32_16x16x32_bf16(af0, bfr, acc[0][nn], 0, 0, 0);
                acc[1][nn] = __builtin_amdgcn_mfma_f32_16x16x32_bf16(af1, bfr, acc[1][nn], 0, 0, 0);
            }
            __builtin_amdgcn_s_barrier();
        }
        // epilogue: only rows m < c are ever read downstream (row c written by stage2s)
#pragma unroll
        for (int mt = 0; mt < 2; ++mt)
#pragma unroll
            for (int nn = 0; nn < 4; ++nn) {
                f32x4 v = acc[mt][nn];
                int hcol = h0 + (w * 4 + nn) * 16 + (l & 15);
#pragma unroll
                for (int r = 0; r < 4; ++r) {
                    int m = mt * 16 + (l >> 4) * 4 + r;
                    if (m < c)
                        nodeB[((size_t)(b * M_ + m)) * H_ + hcol] =
                            __float2bfloat16(v[r] * invL[m]);
                }
            }
    } else if (bid < 512) {
        // ---- cls GEMM split-K -> private slice (plain stores) ----
        float* smem = (float*)smraw;
        float (*As)[64] = (float(*)[64])smem;
        float (*Bs)[64] = (float(*)[64])(smem + 1024);
        int e = bid - 256;
        int bx = e & 31;
        int kg = e >> 5;
        int kbase = kg * 128;
        const float* W;
        float* dst;
        int cbase;
        if (bx < 16) { W = Wnaf; dst = naf8 + (size_t)kg * 64 * H_; cbase = bx * 64; }
        else         { W = Wcd;  dst = cdh8 + (size_t)kg * 64 * H_; cbase = (bx - 16) * 64; }
        int tx = tid % 16, ty = tid / 16;
        float c[4][4] = {};
        int la_row = tid / 4;
        int la_k4  = (tid % 4) * 4;
        int lb_k   = tid / 16;
        int lb_c4  = (tid % 16) * 4;
        for (int k0 = 0; k0 < 128; k0 += 16) {
            float4 a = *(const float4*)(seq + (size_t)la_row * S_ * H_ + kbase + k0 + la_k4);
            *(float4*)(&Bs[lb_k][lb_c4]) =
                *(const float4*)(W + (size_t)(kbase + k0 + lb_k) * H_ + cbase + lb_c4);
            As[la_k4 + 0][la_row] = a.x;
            As[la_k4 + 1][la_row] = a.y;
            As[la_k4 + 2][la_row] = a.z;
            As[la_k4 + 3][la_row] = a.w;
            __syncthreads();
#pragma unroll
            for (int kk = 0; kk < 16; ++kk) {
                float4 av = *(const float4*)(&As[kk][ty * 4]);
                float4 bv = *(const float4*)(&Bs[kk][tx * 4]);
                c[0][0] += av.x * bv.x; c[0][1] += av.x * bv.y; c[0][2] += av.x * bv.z; c[0][3] += av.x * bv.w;
                c[1][0] += av.y * bv.x; c[1][1] += av.y * bv.y; c[1][2] += av.y * bv.z; c[1][3] += av.y * bv.w;
                c[2][0] += av.z * bv.x; c[2][1] += av.z * bv.y; c[2][2] += av.z * bv.z; c[2][3] += av.z * bv.w;
                c[3][0] += av.w * bv.x; c[3][1] += av.w * bv.y; c[3][2] += av.w * bv.z; c[3][3] += av.w * bv.w;
            }
            __syncthreads();
        }
#pragma unroll
        for (int i = 0; i < 4; ++i) {
            float4 v = make_float4(c[i][0], c[i][1], c[i][2], c[i][3]);
            *(float4*)(dst + (size_t)(ty * 4 + i) * H_ + cbase + tx * 4) = v;
        }
    } else if (bid < 3584) {
        // ---- prep: Wt (3072 x 1024 bf16) = transposed [Wnd ; W1+W3 ; W2-W3] ----
        float (*T)[33] = (float(*)[33])smraw;
        int idx = bid - 512;
        int s = idx >> 10, rem = idx & 1023;
        int bx = rem & 31, by = rem >> 5;
        int c = tid & 31, r0 = tid >> 5;
        const int HH = H_ * H_;
#pragma unroll
        for (int i = 0; i < 4; ++i) {
            int r = r0 + 8 * i;
            size_t k = by * 32 + r, n = bx * 32 + c;
            float v;
            if (s == 0)      v = Wnd[k * H_ + n];
            else if (s == 1) v = Wed[k * H_ + n] + Wed[2 * HH + k * H_ + n];
            else             v = Wed[HH + k * H_ + n] - Wed[2 * HH + k * H_ + n];
            T[r][c] = v;
        }
        __syncthreads();
#pragma unroll
        for (int i = 0; i < 4; ++i) {
            int rr = r0 + 8 * i;
            Wt[(size_t)(s * H_ + bx * 32 + rr) * H_ + by * 32 + c] = __float2bfloat16(T[c][rr]);
        }
    } else if (bid == 3584) {
        // ---- count + base prefix + rowmap ----
        int* cnt_s = (int*)smraw;            // [64]
        int* base_s = (int*)smraw + 64;      // [65]
        if (tid < 64) {
            int b = tid, c = 0;
            for (int m = 0; m < M_ - 1; ++m) c += (off[b * (M_ - 1) + m] > 0) ? 1 : 0;
            cnt_s[b] = c; count[b] = c;
        }
        __syncthreads();
        if (tid == 0) {
            int a = 0;
            for (int b = 0; b < 64; ++b) { base_s[b] = a; a += cnt_s[b] + 1; }
            base_s[64] = a;
        }
        __syncthreads();
        if (tid < 65) base[tid] = base_s[tid];
        if (tid < 64) {
            int b = tid, bs = base_s[b];
            for (int m = 0; m <= cnt_s[b]; ++m) rowmap[bs + m] = b * M_ + m;
        }
    } else {
        // ---- constants: econ = tanh(bed)@Weo+beo ; nconst = tanh(bnd)@Wno+bno ----
        float* s0 = (float*)smraw; float* s1 = (float*)smraw + 256;
        float a0 = 0.f, a1 = 0.f;
        for (int h = tid; h < H_; h += 256) {
            float t = tanh_fast(bed[h]);
            a0 += t * Weo[h * 2 + 0];
            a1 += t * Weo[h * 2 + 1];
        }
        s0[tid] = a0; s1[tid] = a1; __syncthreads();
        for (int o = 128; o > 0; o >>= 1) {
            if (tid < o) { s0[tid] += s0[tid + o]; s1[tid] += s1[tid + o]; }
            __syncthreads();
        }
        if (tid == 0) { econ[0] = s0[0] + beo[0]; econ[1] = s1[0] + beo[1]; }
        __syncthreads();
        a0 = 0.f; a1 = 0.f;
        for (int h = tid; h < H_; h += 256) {
            float t = tanh_fast(bnd[h]);
            a0 += t * Wno[h * 2 + 0];
            a1 += t * Wno[h * 2 + 1];
        }
        s0[tid] = a0; s1[tid] = a1; __syncthreads();
        for (int o = 128; o > 0; o >>= 1) {
            if (tid < o) { s0[tid] += s0[tid + o]; s1[tid] += s1[tid + o]; }
            __syncthreads();
        }
        if (tid == 0) { nconst[0] = s0[0] + bno[0]; nconst[1] = s1[0] + bno[1]; }
    }
}

// ================= K_STAGE2S: sum cls slices -> naf row bf16 | cls logits =============
// [0,64) naf: nodeB[b*26+cnt] = sum_kg naf8[kg][b] + bnaf; [64,128) cls logits from cdh8
__global__ __launch_bounds__(256) void k_stage2s(
    const float* __restrict__ naf8, const float* __restrict__ cdh8,
    const float* __restrict__ bnaf, const int* __restrict__ count,
    __hip_bfloat16* __restrict__ nodeB,
    const float* __restrict__ bcd, const float* __restrict__ Wco,
    const float* __restrict__ bco, float* __restrict__ out) {
    __shared__ float smem[512];
    int bid = blockIdx.x;
    int tid = threadIdx.x;
    if (bid < 64) {
        int b = bid, cnt = count[b];
        float4 a = make_float4(0.f, 0.f, 0.f, 0.f);
#pragma unroll
        for (int kg = 0; kg < 8; ++kg) {
            float4 s = ((const float4*)(naf8 + (size_t)kg * 64 * H_ + (size_t)b * H_))[tid];
            a.x += s.x; a.y += s.y; a.z += s.z; a.w += s.w;
        }
        float4 bb = ((const float4*)bnaf)[tid];
        __hip_bfloat16 __attribute__((aligned(8))) h[4] = {
            __float2bfloat16(a.x + bb.x), __float2bfloat16(a.y + bb.y),
            __float2bfloat16(a.z + bb.z), __float2bfloat16(a.w + bb.w)};
        *(ushort4*)(nodeB + ((size_t)(b * M_ + cnt)) * H_ + tid * 4) = *(const ushort4*)h;
    } else {
        // vectorized: each thread owns float4 at h = tid*4 (256*4 = 1024 = H exactly)
        int b = bid - 64;
        float* s0 = smem; float* s1 = smem + 256;
        float4 a = make_float4(0.f, 0.f, 0.f, 0.f);
#pragma unroll
        for (int kg = 0; kg < 8; ++kg) {
            float4 s = ((const float4*)(cdh8 + (size_t)kg * 64 * H_ + (size_t)b * H_))[tid];
            a.x += s.x; a.y += s.y; a.z += s.z; a.w += s.w;
        }
        float4 bb = ((const float4*)bcd)[tid];
        int h = tid * 4;
        float t0 = tanh_fast(a.x + bb.x), t1 = tanh_fast(a.y + bb.y);
        float t2 = tanh_fast(a.z + bb.z), t3 = tanh_fast(a.w + bb.w);
        float a0 = t0 * Wco[h * 2 + 0] + t1 * Wco[h * 2 + 2] + t2 * Wco[h * 2 + 4] + t3 * Wco[h * 2 + 6];
        float a1 = t0 * Wco[h * 2 + 1] + t1 * Wco[h * 2 + 3] + t2 * Wco[h * 2 + 5] + t3 * Wco[h * 2 + 7];
        s0[tid] = a0; s1[tid] = a1; __syncthreads();
        for (int o = 128; o > 0; o >>= 1) {
            if (tid < o) { s0[tid] += s0[tid + o]; s1[tid] += s1[tid + o]; }
            __syncthreads();
        }
        if (tid == 0) { out[b * 2 + 0] = s0[0] + bco[0]; out[b * 2 + 1] = s1[0] + bco[1]; }
    }
}

// ================= STAGE 3: row-compacted MFMA GEMM, BK=64 double-buffered ===========
#define GM 1664
#define GN 3072
#define GK 1024
__global__ __launch_bounds__(256) void k_mfma(const __hip_bfloat16* __restrict__ A,
                                              const __hip_bfloat16* __restrict__ Bt,
                                              float* __restrict__ C,
                                              const int* __restrict__ rowmap,
                                              const int* __restrict__ base) {
    // [buf][khalf] panels of 128 rows x 32 k (row-major), 8 KB each -> 64 KB total
    __shared__ __attribute__((aligned(16))) __hip_bfloat16 As[2][2][4096];
    __shared__ __attribute__((aligned(16))) __hip_bfloat16 Bs[2][2][4096];
    int rowtotal = base[64];
    int row0 = blockIdx.y * 128;
    if (row0 >= rowtotal) return;          // block-uniform early exit
    int tid = threadIdx.x;
    int wid = tid >> 6, ln = tid & 63;
    int col0 = blockIdx.x * 128;
    int ai0 = row0 + wid * 16 + (ln >> 2);      if (ai0 > rowtotal - 1) ai0 = rowtotal - 1;
    int ai1 = row0 + 64 + wid * 16 + (ln >> 2); if (ai1 > rowtotal - 1) ai1 = rowtotal - 1;
    const __hip_bfloat16* ga0 = A + (size_t)rowmap[ai0] * GK + (ln & 3) * 8;
    const __hip_bfloat16* ga1 = A + (size_t)rowmap[ai1] * GK + (ln & 3) * 8;
    const __hip_bfloat16* gb0 = Bt + (size_t)(col0 + wid * 16 + (ln >> 2)) * GK + (ln & 3) * 8;
    const __hip_bfloat16* gb1 = gb0 + (size_t)64 * GK;
    int lo = wid * 512;                    // per-wave element base within a panel
    int mrow = (wid >> 1) * 64, ncol = (wid & 1) * 64;
    int l15 = ln & 15, l4 = ln >> 4;
    f32x4 acc[4][4] = {};

#define STAGE(buf, kt)                                                      \
    do {                                                                    \
        int kb_ = (kt) * 64;                                                \
        gload16(ga0 + kb_,      &As[buf][0][0]    + lo);                    \
        gload16(ga0 + kb_ + 32, &As[buf][1][0]    + lo);                    \
        gload16(ga1 + kb_,      &As[buf][0][2048] + lo);                    \
        gload16(ga1 + kb_ + 32, &As[buf][1][2048] + lo);                    \
        gload16(gb0 + kb_,      &Bs[buf][0][0]    + lo);                    \
        gload16(gb0 + kb_ + 32, &Bs[buf][1][0]    + lo);                    \
        gload16(gb1 + kb_,      &Bs[buf][0][2048] + lo);                    \
        gload16(gb1 + kb_ + 32, &Bs[buf][1][2048] + lo);                    \
    } while (0)

    STAGE(0, 0);
    for (int kt = 0; kt < 16; ++kt) {
        int cur = kt & 1;
        if (kt + 1 < 16) {
            STAGE(cur ^ 1, kt + 1);
            asm volatile("s_waitcnt vmcnt(8)" ::: "memory");   // tile kt landed
        } else {
            asm volatile("s_waitcnt vmcnt(0)" ::: "memory");
        }
        __builtin_amdgcn_s_barrier();
#pragma unroll
        for (int kk = 0; kk < 2; ++kk) {
            const __hip_bfloat16* pa = &As[cur][kk][0] + (mrow + l15) * 32 + l4 * 8;
            const __hip_bfloat16* pb = &Bs[cur][kk][0] + (ncol + l15) * 32 + l4 * 8;
            bf16x8 af[4], bfv[4];
#pragma unroll
            for (int mi = 0; mi < 4; ++mi) af[mi] = *(const bf16x8*)(pa + mi * 16 * 32);
#pragma unroll
            for (int ni = 0; ni < 4; ++ni) bfv[ni] = *(const bf16x8*)(pb + ni * 16 * 32);
#pragma unroll
            for (int mi = 0; mi < 4; ++mi)
#pragma unroll
                for (int ni = 0; ni < 4; ++ni)
                    acc[mi][ni] = __builtin_amdgcn_mfma_f32_16x16x32_bf16(af[mi], bfv[ni],
                                                                          acc[mi][ni], 0, 0, 0);
        }
        __builtin_amdgcn_s_barrier();      // reads done before next STAGE overwrites
    }
#undef STAGE
#pragma unroll
    for (int mi = 0; mi < 4; ++mi)
#pragma unroll
        for (int ni = 0; ni < 4; ++ni) {
            f32x4 v = acc[mi][ni];
            int r = row0 + mrow + mi * 16 + l4 * 4;
            size_t cc = col0 + ncol + ni * 16 + l15;
#pragma unroll
            for (int j = 0; j < 4; ++j)
                if (r + j < rowtotal) C[(size_t)(r + j) * GN + cc] = v[j];
        }
}

// ================= STAGE 4: node logits | edge logits (compact C rows) ===============
// blocks [0,416) node (4 rows each); [416,1440) edge (bx = e&15, b = e>>4)
__global__ __launch_bounds__(256) void k_stage4(
    const float* __restrict__ Cm, const int* __restrict__ count,
    const int* __restrict__ base, const float* __restrict__ bnd,
    const float* __restrict__ Wno, const float* __restrict__ bno,
    const float* __restrict__ bed, const float* __restrict__ Weo,
    const float* __restrict__ beo, const float* __restrict__ econ,
    const float* __restrict__ nconst, float* __restrict__ out_n,
    float* __restrict__ out_e) {
    int bid = blockIdx.x;
    int wid = threadIdx.x >> 6, lane = threadIdx.x & 63;
    if (bid < 416) {
        int r = bid * 4 + wid;
        int b = r / 26, m = r - b * 26;
        if (m <= count[b]) {
            const float4* src = (const float4*)(Cm + (size_t)(base[b] + m) * GN);
            float a0 = 0.f, a1 = 0.f;
#pragma unroll
            for (int it = 0; it < 4; ++it) {
                int h = lane * 4 + it * 256;
                float4 s = src[lane + it * 64];
                float4 bb = *(const float4*)(bnd + h);
                float t0 = tanh_fast(s.x + bb.x), t1 = tanh_fast(s.y + bb.y);
                float t2 = tanh_fast(s.z + bb.z), t3 = tanh_fast(s.w + bb.w);
                a0 += t0 * Wno[h * 2 + 0] + t1 * Wno[h * 2 + 2] + t2 * Wno[h * 2 + 4] + t3 * Wno[h * 2 + 6];
                a1 += t0 * Wno[h * 2 + 1] + t1 * Wno[h * 2 + 3] + t2 * Wno[h * 2 + 5] + t3 * Wno[h * 2 + 7];
            }
            for (int o = 32; o > 0; o >>= 1) { a0 += __shfl_down(a0, o); a1 += __shfl_down(a1, o); }
            if (lane == 0) { out_n[(size_t)r * 2 + 0] = a0 + bno[0]; out_n[(size_t)r * 2 + 1] = a1 + bno[1]; }
        } else if (lane == 0) {
            out_n[(size_t)r * 2 + 0] = nconst[0];
            out_n[(size_t)r * 2 + 1] = nconst[1];
        }
    } else {
        int e = bid - 416;
        int b = e >> 4;
        int blk16 = e & 15;
        int wg = blk16 * 4 + wid;
        int n = count[b] + 1;
        int n2 = n * n;
        int bb_ = base[b];
        float4 bed4[4], w04[4], w14[4];
#pragma unroll
        for (int it = 0; it < 4; ++it) {
            int h = lane * 4 + it * 256;
            bed4[it] = *(const float4*)(bed + h);
            w04[it] = make_float4(Weo[h * 2 + 0], Weo[h * 2 + 2], Weo[h * 2 + 4], Weo[h * 2 + 6]);
            w14[it] = make_float4(Weo[h * 2 + 1], Weo[h * 2 + 3], Weo[h * 2 + 5], Weo[h * 2 + 7]);
        }
        float b0 = beo[0], b1 = beo[1];
        for (int k = wg; k < n2; k += 64) {
            float* dst = out_e + ((size_t)b * E_ + k) * 2;
            int i = k / n, j = k - i * n;
            const float4* U4 = (const float4*)(Cm + (size_t)(bb_ + j) * GN + H_);
            const float4* V4 = (const float4*)(Cm + (size_t)(bb_ + i) * GN + 2 * H_);
            float a0 = 0.f, a1 = 0.f;
#pragma unroll
            for (int it = 0; it < 4; ++it) {
                float4 u = U4[lane + it * 64];
                float4 v = V4[lane + it * 64];
                float t0 = tanh_fast(u.x + v.x + bed4[it].x);
                float t1 = tanh_fast(u.y + v.y + bed4[it].y);
                float t2 = tanh_fast(u.z + v.z + bed4[it].z);
                float t3 = tanh_fast(u.w + v.w + bed4[it].w);
                a0 += t0 * w04[it].x + t1 * w04[it].y + t2 * w04[it].z + t3 * w04[it].w;
                a1 += t0 * w14[it].x + t1 * w14[it].y + t2 * w14[it].z + t3 * w14[it].w;
            }
            for (int o = 32; o > 0; o >>= 1) { a0 += __shfl_down(a0, o); a1 += __shfl_down(a1, o); }
            if (lane == 0) { dst[0] = a0 + b0; dst[1] = a1 + b1; }
        }
        // invalid-edge tail [n2, E): contiguous constant (e0,e1) region,
        // filled cooperatively & coalesced by block 0 of this b
        if (blk16 == 0) {
            float e0 = econ[0], e1 = econ[1];
            float* dste = out_e + (size_t)b * E_ * 2;
            for (int idx = 2 * n2 + (int)threadIdx.x; idx < 2 * E_; idx += 256)
                dste[idx] = (idx & 1) ? e1 : e0;
        }
    }
}

extern "C" void kernel_launch(void* const* d_in, const int* in_sizes, int n_in,
                              void* d_out, int out_size, void* d_ws, size_t ws_size,
                              hipStream_t stream) {
    const float* seq  = (const float*)d_in[0];
    const int*   off  = (const int*)d_in[1];
    const float* Wnaf = (const float*)d_in[4];  const float* bnaf = (const float*)d_in[5];
    const float* Wcd  = (const float*)d_in[6];  const float* bcd  = (const float*)d_in[7];
    const float* Wco  = (const float*)d_in[8];  const float* bco  = (const float*)d_in[9];
    const float* Wnd  = (const float*)d_in[10]; const float* bnd  = (const float*)d_in[11];
    const float* Wno  = (const float*)d_in[12]; const float* bno  = (const float*)d_in[13];
    const float* Wed  = (const float*)d_in[14]; const float* bed  = (const float*)d_in[15];
    const float* Weo  = (const float*)d_in[16]; const float* beo  = (const float*)d_in[17];
    float* out = (float*)d_out;

    float* ws = (float*)d_ws;
    size_t p = 0;
    float* naf8  = ws + p;  p += (size_t)8 * 64 * H_;            // write-only slices
    float* cdh8  = ws + p;  p += (size_t)8 * 64 * H_;
    __hip_bfloat16* nodeB = (__hip_bfloat16*)(ws + p); p += (size_t)B_ * M_ * H_ / 2;
    __hip_bfloat16* Wt    = (__hip_bfloat16*)(ws + p); p += (size_t)3 * H_ * H_ / 2;
    float* Cbuf  = ws + p;  p += (size_t)GM * GN;
    int*   cnt   = (int*)(ws + p); p += 64;
    int*   base  = (int*)(ws + p); p += 65;
    int*   rowmap = (int*)(ws + p); p += GM;
    float* econ  = ws + p;  p += 2;
    float* nconst = ws + p; p += 2;

    // no memset needed: all consumed workspace is fully written before read

    k_stage1<<<dim3(3586), 256, 0, stream>>>(seq, off, Wnaf, Wcd, Wnd, Wed, bed, Weo, beo,
                                             bnd, Wno, bno, Wt, cnt, base, rowmap,
                                             econ, nconst, naf8, cdh8, nodeB);
    k_stage2s<<<dim3(128), 256, 0, stream>>>(naf8, cdh8, bnaf, cnt, nodeB,
                                             bcd, Wco, bco, out);
    k_mfma<<<dim3(GN / 128, GM / 128), 256, 0, stream>>>(nodeB, Wt, Cbuf, rowmap, base);
    k_stage4<<<dim3(1440), 256, 0, stream>>>(Cbuf, cnt, base, bnd, Wno, bno, bed, Weo, beo,
                                             econ, nconst,
                                             out + B_ * 2, out + B_ * 2 + B_ * M_ * 2);
}